// Round 3
// baseline (294.454 us; speedup 1.0000x reference)
//
#include <hip/hip_runtime.h>
#include <hip/hip_bf16.h>
#include <math.h>

#define LATENT 256
#define HIDDEN 512
#define NODE_F 128
#define MAX_NODES 50
#define NPAIRS 1225        // 50*49/2
#define BATCH 128
#define NODE_OUT 6400      // MAX_NODES*NODE_F
#define MTILE 32           // edge rows per tile (R14: halved for 2 blocks/CU)
#define TPB 10             // tiles per block (40 tile-slots/batch = 4 blocks/batch)
#define NBLK 512           // edge grid (2 blocks/CU, one full pass)

typedef __attribute__((ext_vector_type(8))) short short8;
typedef __attribute__((ext_vector_type(4))) float float4v;

union S8U { short8 s; unsigned int u[4]; };

__device__ __forceinline__ float bf2f(ushort u) {
    union { unsigned int i; float f; } v; v.i = ((unsigned int)u) << 16; return v.f;
}
__device__ __forceinline__ ushort f2bf(float f) {
    union { unsigned int i; float f; } v; v.f = f;
    unsigned int r = v.i + 0x7fffu + ((v.i >> 16) & 1u);   // RNE
    return (ushort)(r >> 16);
}
__device__ __forceinline__ unsigned int pk_bf16(float f0, float f1) {
    __hip_bfloat162 p = __float22bfloat162_rn(float2{f0, f1});   // v_cvt_pk_bf16_f32 (RNE)
    unsigned int w; __builtin_memcpy(&w, &p, 4); return w;
}
__device__ __forceinline__ float sigmoidf(float x) {
    return 1.0f / (1.0f + __expf(-x));
}

// ================= fused prep kernel (R11 layout — measured-good) =================
// [0,800)      nw3T 64x64-tile transpose
// [800,832)    ew2T 64x64-tile transpose (8 k-tiles x 4 n-tiles)
// [832,848)    wijT U-half tiles (2 k x 8 n)
// [848,864)    wijT V-half tiles (2 k x 8 n)
// [864,1120)   Zc = z @ W_z + eb1
// [1120,1376)  fused node MLP L1+L2 -> h2b
// [1376,1381)  ptab
#define TR3_B0   0
#define EW2_B0   800
#define WIU_B0   832
#define WIV_B0   848
#define ZC_B0    864
#define ND_B0    1120
#define PT_B0    1376
#define PREPK_NB 1381

__global__ __launch_bounds__(256) void k_prep_all(
    const float* __restrict__ nw3, ushort* __restrict__ nw3T,
    const float* __restrict__ ew1, const float* __restrict__ ew2,
    ushort* __restrict__ ew2T, ushort* __restrict__ wijT,
    const float* __restrict__ z, const float* __restrict__ eb1,
    float* __restrict__ Zc,
    const float* __restrict__ nw1, const float* __restrict__ nb1,
    const float* __restrict__ nw2, const float* __restrict__ nb2,
    ushort* __restrict__ h2b, int* __restrict__ ptab)
{
    __shared__ float smem[64 * 65];
    int b = blockIdx.x;
    int tid = threadIdx.x;
    int tx = tid & 63, ty = tid >> 6;   // 64 x 4

    if (b < EW2_B0) {
        // ---- nw3 transpose, 64x64 tiles (8 k-tiles x 100 n-tiles)
        int bb = b - TR3_B0;
        int k0 = (bb & 7) * 64;
        int n0 = (bb >> 3) * 64;
#pragma unroll
        for (int r = 0; r < 16; r++) {
            int row = r * 4 + ty;
            smem[row * 65 + tx] = nw3[(k0 + row) * NODE_OUT + n0 + tx];
        }
        __syncthreads();
#pragma unroll
        for (int c = 0; c < 16; c++) {
            int n = c * 4 + ty;
            nw3T[(size_t)(n0 + n) * HIDDEN + k0 + tx] = f2bf(smem[tx * 65 + n]);
        }
    } else if (b < WIU_B0) {
        // ---- ew2T[n][k] = ew2[k][n], tiled: ew2 is 512x256
        int bb = b - EW2_B0;
        int k0 = (bb >> 2) * 64;
        int n0 = (bb & 3) * 64;
#pragma unroll
        for (int r = 0; r < 16; r++) {
            int row = r * 4 + ty;
            smem[row * 65 + tx] = ew2[(k0 + row) * 256 + n0 + tx];
        }
        __syncthreads();
#pragma unroll
        for (int c = 0; c < 16; c++) {
            int n = c * 4 + ty;
            ew2T[(n0 + n) * HIDDEN + k0 + tx] = f2bf(smem[tx * 65 + n]);
        }
    } else if (b < WIV_B0) {
        // ---- wijT U-half: wijT[n][k] = ew1[256+k][n], n<512, k<128
        int bb = b - WIU_B0;
        int k0 = (bb >> 3) * 64;
        int n0 = (bb & 7) * 64;
#pragma unroll
        for (int r = 0; r < 16; r++) {
            int row = r * 4 + ty;
            smem[row * 65 + tx] = ew1[(256 + k0 + row) * 512 + n0 + tx];
        }
        __syncthreads();
#pragma unroll
        for (int c = 0; c < 16; c++) {
            int n = c * 4 + ty;
            wijT[(n0 + n) * NODE_F + k0 + tx] = f2bf(smem[tx * 65 + n]);
        }
    } else if (b < ZC_B0) {
        // ---- wijT V-half: wijT[512+n][k] = ew1[384+k][n], n<512, k<128
        int bb = b - WIV_B0;
        int k0 = (bb >> 3) * 64;
        int n0 = (bb & 7) * 64;
#pragma unroll
        for (int r = 0; r < 16; r++) {
            int row = r * 4 + ty;
            smem[row * 65 + tx] = ew1[(384 + k0 + row) * 512 + n0 + tx];
        }
        __syncthreads();
#pragma unroll
        for (int c = 0; c < 16; c++) {
            int n = c * 4 + ty;
            wijT[(512 + n0 + n) * NODE_F + k0 + tx] = f2bf(smem[tx * 65 + n]);
        }
    } else if (b < ND_B0) {
        // ---- Zc = z @ W_z + eb1
        int b2 = b - ZC_B0;
        int r = b2 >> 1, o = (b2 & 1) * 256 + tid;
        float* zs = smem;
        zs[tid] = z[r * LATENT + tid];
        __syncthreads();
        float acc = 0.f;
#pragma unroll 8
        for (int k = 0; k < LATENT; k++) acc += zs[k] * ew1[k * HIDDEN + o];
        Zc[r * HIDDEN + o] = acc + eb1[o];
    } else if (b < PT_B0) {
        // ---- fused node MLP L1+L2
        int b2 = b - ND_B0;
        int r = b2 >> 1, half = b2 & 1;
        float* zs = smem;            // 256 floats
        float* hs = smem + 256;      // 512 floats
        zs[tid] = z[r * LATENT + tid];
        __syncthreads();
        float a0 = 0.f, a1 = 0.f;
#pragma unroll 8
        for (int k = 0; k < LATENT; k++) {
            float zk = zs[k];
            a0 += zk * nw1[k * HIDDEN + tid];
            a1 += zk * nw1[k * HIDDEN + tid + 256];
        }
        hs[tid]       = fmaxf(a0 + nb1[tid], 0.f);
        hs[tid + 256] = fmaxf(a1 + nb1[tid + 256], 0.f);
        __syncthreads();
        int o = half * 256 + tid;
        float acc = 0.f;
#pragma unroll 8
        for (int k = 0; k < HIDDEN; k++) acc += hs[k] * nw2[k * HIDDEN + o];
        acc += nb2[o];
        h2b[r * HIDDEN + o] = f2bf(fmaxf(acc, 0.f));
    } else {
        int p = (b - PT_B0) * 256 + tid;
        if (p < NPAIRS) {
            int i = 0, off = 0;
            while (p - off >= MAX_NODES - 1 - i) { off += MAX_NODES - 1 - i; ++i; }
            int j = i + 1 + (p - off);
            ptab[p] = (i << 8) | j;
        }
    }
}

// ---------------- node layer 3 via MFMA: grid 200 = 100 n-tiles(64) x 2 m-halves(64)
// (R11 version — measured-good; R13 re-tile regressed, reverted)
__global__ __launch_bounds__(256, 4) void k_node_out_mfma(
    const ushort* __restrict__ h2b, const ushort* __restrict__ nw3T,
    const float* __restrict__ nb3, float* __restrict__ node_probs,
    ushort* __restrict__ node_feats)
{
    int tid = threadIdx.x;
    int wave = tid >> 6, lane = tid & 63;
    int m16 = lane & 15, quad = lane >> 4;
    int n0 = (blockIdx.x >> 1) * 64;
    int m0 = (blockIdx.x & 1) * 64;
    int col = n0 + wave * 16 + m16;

    float4v acc[4];
#pragma unroll
    for (int mt = 0; mt < 4; mt++) acc[mt] = (float4v)(0.f);

    const ushort* bb = nw3T + (size_t)col * HIDDEN;
#pragma unroll
    for (int it = 0; it < 16; ++it) {
        int kk = it * 32 + quad * 8;
        short8 b = *(const short8*)(bb + kk);
#pragma unroll
        for (int mt = 0; mt < 4; mt++) {
            short8 a = *(const short8*)(h2b + (m0 + mt * 16 + m16) * HIDDEN + kk);
            acc[mt] = __builtin_amdgcn_mfma_f32_16x16x32_bf16(a, b, acc[mt], 0, 0, 0);
        }
    }
    float bias = nb3[col];
#pragma unroll
    for (int mt = 0; mt < 4; mt++)
#pragma unroll
        for (int t = 0; t < 4; t++) {
            int row = m0 + mt * 16 + quad * 4 + t;
            float v = acc[mt][t] + bias;
            node_probs[(size_t)row * NODE_OUT + col] = sigmoidf(v);
            node_feats[(size_t)row * NODE_OUT + col] = f2bf(v);
        }
}

// ---------------- UV = node_feats @ [W_i|W_j]   (6400 x 1024, bf16 out)
// (R11 version — measured-good; R13 re-tile regressed, reverted)
__global__ __launch_bounds__(256, 4) void k_uv(
    const ushort* __restrict__ nf, const ushort* __restrict__ wijT,
    ushort* __restrict__ UV)
{
    int tid = threadIdx.x;
    int wave = tid >> 6, lane = tid & 63;
    int m16 = lane & 15, quad = lane >> 4;
    int bm = blockIdx.x >> 2, bn = blockIdx.x & 3;
    int base = bn * 256 + wave * 64;
    int r0 = bm * 64;

    float4v acc[4][4];
#pragma unroll
    for (int mt = 0; mt < 4; mt++)
#pragma unroll
        for (int nt = 0; nt < 4; nt++) acc[mt][nt] = (float4v)(0.f);

#pragma unroll
    for (int k0 = 0; k0 < NODE_F; k0 += 32) {
        int kk = k0 + quad * 8;
        short8 a0 = *(const short8*)(nf + (r0 + m16) * NODE_F + kk);
        short8 a1 = *(const short8*)(nf + (r0 + 16 + m16) * NODE_F + kk);
        short8 a2 = *(const short8*)(nf + (r0 + 32 + m16) * NODE_F + kk);
        short8 a3 = *(const short8*)(nf + (r0 + 48 + m16) * NODE_F + kk);
#pragma unroll
        for (int nt = 0; nt < 4; nt++) {
            int n = base + nt * 16 + m16;
            short8 b = *(const short8*)(wijT + n * NODE_F + kk);
            acc[0][nt] = __builtin_amdgcn_mfma_f32_16x16x32_bf16(a0, b, acc[0][nt], 0, 0, 0);
            acc[1][nt] = __builtin_amdgcn_mfma_f32_16x16x32_bf16(a1, b, acc[1][nt], 0, 0, 0);
            acc[2][nt] = __builtin_amdgcn_mfma_f32_16x16x32_bf16(a2, b, acc[2][nt], 0, 0, 0);
            acc[3][nt] = __builtin_amdgcn_mfma_f32_16x16x32_bf16(a3, b, acc[3][nt], 0, 0, 0);
        }
    }
#pragma unroll
    for (int nt = 0; nt < 4; nt++) {
        int colg = base + nt * 16 + m16;
#pragma unroll
        for (int mt = 0; mt < 4; mt++)
#pragma unroll
            for (int t = 0; t < 4; t++) {
                int rr = r0 + mt * 16 + quad * 4 + t;
                UV[(size_t)rr * 1024 + colg] = f2bf(acc[mt][nt][t]);
            }
    }
}

// ---------------- fused edge, persistent-B, grid 512 (2 blocks/CU)
// R14: MTILE 64->32. LDS 77.6 KB -> 2 blocks/CU (4 waves/SIMD) for latency
// hiding; per-wave ds-read per tile halves; R12 schedule kept verbatim
// (single barrier/tile, part dbuf, deferred out-write, DPP-only reduce).
__global__ __launch_bounds__(512, 4) void k_edge8(
    const float* __restrict__ Zc, const ushort* __restrict__ UV,
    const ushort* __restrict__ ew2T, const float* __restrict__ ew3,
    const float* __restrict__ eb2, const float* __restrict__ eb3,
    const int* __restrict__ ptab, float* __restrict__ out_edges)
{
    __shared__ __align__(16) ushort h1[2][MTILE][HIDDEN + 8]; // 66,560 B
    __shared__ float part[2][MTILE][33];                      //  8,448 B
    __shared__ int uo5[TPB][MTILE], vo5[TPB][MTILE];          //  2,560 B
    // total 77,568 B <= 80 KiB -> 2 blocks/CU

    int tid  = threadIdx.x;
    int blk  = blockIdx.x;
    int b    = blk >> 2;                  // 4 blocks/batch
    int ti0  = (blk & 3) * TPB;           // 40 tile-slots/batch (39 real)

    if (tid < MTILE) {
#pragma unroll
        for (int t = 0; t < TPB; t++) {
            int p = (ti0 + t) * MTILE + tid;
            if (p >= NPAIRS) p = NPAIRS - 1;
            int ij = ptab[p];
            uo5[t][tid] = (b * MAX_NODES + (ij >> 8)) * 1024;
            vo5[t][tid] = (b * MAX_NODES + (ij & 255)) * 1024 + 512;
        }
    }

    int wave = tid >> 6, lane = tid & 63;
    int m16 = lane & 15, quad = lane >> 4;
    int c8 = lane * 8;
    int kk0 = quad * 8;

    float4v zA = *(const float4v*)(Zc + b * HIDDEN + c8);
    float4v zB = *(const float4v*)(Zc + b * HIDDEN + c8 + 4);

    const ushort* bb0 = ew2T + (wave * 32 + m16) * HIDDEN;
    const ushort* bb1 = ew2T + (wave * 32 + 16 + m16) * HIDDEN;
    short8 Breg[16][2];
#pragma unroll
    for (int kc = 0; kc < 16; kc++) {
        Breg[kc][0] = *(const short8*)(bb0 + kc * 32 + kk0);
        Breg[kc][1] = *(const short8*)(bb1 + kc * 32 + kk0);
    }
    float eb2v[2], ew3v[2];
    eb2v[0] = eb2[wave * 32 + m16];      eb2v[1] = eb2[wave * 32 + 16 + m16];
    ew3v[0] = ew3[wave * 32 + m16];      ew3v[1] = ew3[wave * 32 + 16 + m16];

    __syncthreads();

    // ---- prologue: build tile 0 into h1[0] (4 rows per wave)
#pragma unroll
    for (int rr = 0; rr < 4; rr++) {
        int r = wave * 4 + rr;
        short8 u8 = *(const short8*)(UV + uo5[0][r] + c8);
        short8 v8 = *(const short8*)(UV + vo5[0][r] + c8);
        S8U hh;
#pragma unroll
        for (int e2 = 0; e2 < 4; e2++) {
            float z0 = (e2 < 2) ? zA[e2 * 2] : zB[e2 * 2 - 4];
            float z1 = (e2 < 2) ? zA[e2 * 2 + 1] : zB[e2 * 2 - 3];
            float f0 = fmaxf(z0 + bf2f((ushort)u8[e2 * 2]) + bf2f((ushort)v8[e2 * 2]), 0.f);
            float f1 = fmaxf(z1 + bf2f((ushort)u8[e2 * 2 + 1]) + bf2f((ushort)v8[e2 * 2 + 1]), 0.f);
            hh.u[e2] = pk_bf16(f0, f1);
        }
        *(short8*)&h1[0][r][c8] = hh.s;
    }
    __syncthreads();

    for (int t = 0; t < TPB; t++) {
        int cur = t & 1, nxt = cur ^ 1;
        bool hasNext = (t + 1 < TPB);

        // ---- deferred edge-output write for tile t-1 (overlaps other waves' MFMA)
        if (t > 0 && tid < MTILE) {
            int p = (ti0 + t - 1) * MTILE + tid;
            if (p < NPAIRS) {
                float v = eb3[0];
#pragma unroll
                for (int w = 0; w < 32; w++) v += part[nxt][tid][w];
                out_edges[b * NPAIRS + p] = sigmoidf(v);
            }
        }

        float4v acc2[2][2];
#pragma unroll
        for (int mt = 0; mt < 2; mt++)
#pragma unroll
            for (int nt = 0; nt < 2; nt++) acc2[mt][nt] = (float4v)(0.f);

        short8 uu[2], vv[2];
        if (hasNext) {
#pragma unroll
            for (int rr = 0; rr < 2; rr++) {
                int r = wave * 4 + rr;
                uu[rr] = *(const short8*)(UV + uo5[t + 1][r] + c8);
                vv[rr] = *(const short8*)(UV + vo5[t + 1][r] + c8);
            }
        }
#pragma unroll
        for (int it = 0; it < 8; ++it) {
            int kk = it * 32 + kk0;
            short8 a0 = *(const short8*)&h1[cur][m16][kk];
            short8 a1 = *(const short8*)&h1[cur][16 + m16][kk];
            acc2[0][0] = __builtin_amdgcn_mfma_f32_16x16x32_bf16(a0, Breg[it][0], acc2[0][0], 0, 0, 0);
            acc2[1][0] = __builtin_amdgcn_mfma_f32_16x16x32_bf16(a1, Breg[it][0], acc2[1][0], 0, 0, 0);
            acc2[0][1] = __builtin_amdgcn_mfma_f32_16x16x32_bf16(a0, Breg[it][1], acc2[0][1], 0, 0, 0);
            acc2[1][1] = __builtin_amdgcn_mfma_f32_16x16x32_bf16(a1, Breg[it][1], acc2[1][1], 0, 0, 0);
        }
        if (hasNext) {
#pragma unroll
            for (int rr = 0; rr < 2; rr++) {
                int r = wave * 4 + rr;
                S8U hh;
#pragma unroll
                for (int e2 = 0; e2 < 4; e2++) {
                    float z0 = (e2 < 2) ? zA[e2 * 2] : zB[e2 * 2 - 4];
                    float z1 = (e2 < 2) ? zA[e2 * 2 + 1] : zB[e2 * 2 - 3];
                    float f0 = fmaxf(z0 + bf2f((ushort)uu[rr][e2 * 2]) + bf2f((ushort)vv[rr][e2 * 2]), 0.f);
                    float f1 = fmaxf(z1 + bf2f((ushort)uu[rr][e2 * 2 + 1]) + bf2f((ushort)vv[rr][e2 * 2 + 1]), 0.f);
                    hh.u[e2] = pk_bf16(f0, f1);
                }
                *(short8*)&h1[nxt][r][c8] = hh.s;
            }
#pragma unroll
            for (int rr = 0; rr < 2; rr++) {
                int r = wave * 4 + 2 + rr;
                uu[rr] = *(const short8*)(UV + uo5[t + 1][r] + c8);
                vv[rr] = *(const short8*)(UV + vo5[t + 1][r] + c8);
            }
        }
#pragma unroll
        for (int it = 8; it < 16; ++it) {
            int kk = it * 32 + kk0;
            short8 a0 = *(const short8*)&h1[cur][m16][kk];
            short8 a1 = *(const short8*)&h1[cur][16 + m16][kk];
            acc2[0][0] = __builtin_amdgcn_mfma_f32_16x16x32_bf16(a0, Breg[it][0], acc2[0][0], 0, 0, 0);
            acc2[1][0] = __builtin_amdgcn_mfma_f32_16x16x32_bf16(a1, Breg[it][0], acc2[1][0], 0, 0, 0);
            acc2[0][1] = __builtin_amdgcn_mfma_f32_16x16x32_bf16(a0, Breg[it][1], acc2[0][1], 0, 0, 0);
            acc2[1][1] = __builtin_amdgcn_mfma_f32_16x16x32_bf16(a1, Breg[it][1], acc2[1][1], 0, 0, 0);
        }
        if (hasNext) {
#pragma unroll
            for (int rr = 0; rr < 2; rr++) {
                int r = wave * 4 + 2 + rr;
                S8U hh;
#pragma unroll
                for (int e2 = 0; e2 < 4; e2++) {
                    float z0 = (e2 < 2) ? zA[e2 * 2] : zB[e2 * 2 - 4];
                    float z1 = (e2 < 2) ? zA[e2 * 2 + 1] : zB[e2 * 2 - 3];
                    float f0 = fmaxf(z0 + bf2f((ushort)uu[rr][e2 * 2]) + bf2f((ushort)vv[rr][e2 * 2]), 0.f);
                    float f1 = fmaxf(z1 + bf2f((ushort)uu[rr][e2 * 2 + 1]) + bf2f((ushort)vv[rr][e2 * 2 + 1]), 0.f);
                    hh.u[e2] = pk_bf16(f0, f1);
                }
                *(short8*)&h1[nxt][r][c8] = hh.s;
            }
        }

        // ---- reduce: xor1,xor2 only (DPP); 4 partials / 16-lane group -> part[cur]
#pragma unroll
        for (int mt = 0; mt < 2; mt++)
#pragma unroll
            for (int tt = 0; tt < 4; tt++) {
                float s = 0.f;
#pragma unroll
                for (int nt = 0; nt < 2; nt++)
                    s += fmaxf(acc2[mt][nt][tt] + eb2v[nt], 0.f) * ew3v[nt];
                s += __shfl_xor(s, 1);
                s += __shfl_xor(s, 2);
                if ((m16 & 3) == 0)
                    part[cur][mt * 16 + quad * 4 + tt][wave * 4 + (m16 >> 2)] = s;
            }
        __syncthreads();   // single barrier/tile: orders h1 phase flip + part publish
    }

    // ---- tail: edge-output write for the last tile
    if (tid < MTILE) {
        int p = (ti0 + TPB - 1) * MTILE + tid;
        if (p < NPAIRS) {
            float v = eb3[0];
#pragma unroll
            for (int w = 0; w < 32; w++) v += part[(TPB - 1) & 1][tid][w];
            out_edges[b * NPAIRS + p] = sigmoidf(v);
        }
    }
}

extern "C" void kernel_launch(void* const* d_in, const int* in_sizes, int n_in,
                              void* d_out, int out_size, void* d_ws, size_t ws_size,
                              hipStream_t stream) {
    const float* z   = (const float*)d_in[0];
    const float* nw1 = (const float*)d_in[1];
    const float* nb1 = (const float*)d_in[2];
    const float* nw2 = (const float*)d_in[3];
    const float* nb2 = (const float*)d_in[4];
    const float* nw3 = (const float*)d_in[5];
    const float* nb3 = (const float*)d_in[6];
    const float* ew1 = (const float*)d_in[7];
    const float* eb1 = (const float*)d_in[8];
    const float* ew2 = (const float*)d_in[9];
    const float* eb2 = (const float*)d_in[10];
    const float* ew3 = (const float*)d_in[11];
    const float* eb3 = (const float*)d_in[12];

    char* ws = (char*)d_ws;
    int*    ptab = (int*)(ws);                       // 1225*4
    ushort* h2b  = (ushort*)(ws + 262144);           // 131072
    ushort* nf   = (ushort*)(ws + 393216);           // 1638400
    ushort* ew2T = (ushort*)(ws + 2031616);          // 262144
    ushort* wijT = (ushort*)(ws + 2293760);          // 262144
    ushort* nw3T = (ushort*)(ws + 2555904);          // 6553600
    float*  Zc   = (float*)(ws + 9109504);           // 262144
    ushort* UV   = (ushort*)(ws + 9371648);          // 13107200

    float* out_nodes = (float*)d_out;                // 128*6400
    float* out_edges = out_nodes + BATCH * NODE_OUT; // 128*1225

    k_prep_all<<<PREPK_NB, 256, 0, stream>>>(nw3, nw3T, ew1, ew2, ew2T, wijT,
                                             z, eb1, Zc, nw1, nb1, nw2, nb2,
                                             h2b, ptab);
    k_node_out_mfma<<<200, 256, 0, stream>>>(h2b, nw3T, nb3, out_nodes, nf);
    k_uv<<<400, 256, 0, stream>>>(nf, wijT, UV);
    k_edge8<<<NBLK, 512, 0, stream>>>(Zc, UV, ew2T, ew3, eb2, eb3, ptab, out_edges);
}

// Round 4
// 209.581 us; speedup vs baseline: 1.4050x; 1.4050x over previous
//
#include <hip/hip_runtime.h>
#include <hip/hip_bf16.h>
#include <math.h>

#define LATENT 256
#define HIDDEN 512
#define NODE_F 128
#define MAX_NODES 50
#define NPAIRS 1225        // 50*49/2
#define BATCH 128
#define NODE_OUT 6400      // MAX_NODES*NODE_F
#define MTILE 64           // edge rows per tile (R12-measured)
#define TPB 10             // tiles per block (20 tiles/batch = 2 blocks/batch)
#define NBLK 256           // edge grid (1 block/CU)

typedef __attribute__((ext_vector_type(8))) short short8;
typedef __attribute__((ext_vector_type(4))) float float4v;

union S8U { short8 s; unsigned int u[4]; };

__device__ __forceinline__ float bf2f(ushort u) {
    union { unsigned int i; float f; } v; v.i = ((unsigned int)u) << 16; return v.f;
}
__device__ __forceinline__ ushort f2bf(float f) {
    union { unsigned int i; float f; } v; v.f = f;
    unsigned int r = v.i + 0x7fffu + ((v.i >> 16) & 1u);   // RNE
    return (ushort)(r >> 16);
}
__device__ __forceinline__ unsigned int pk_bf16(float f0, float f1) {
    __hip_bfloat162 p = __float22bfloat162_rn(float2{f0, f1});   // v_cvt_pk_bf16_f32 (RNE)
    unsigned int w; __builtin_memcpy(&w, &p, 4); return w;
}
__device__ __forceinline__ float sigmoidf(float x) {
    return 1.0f / (1.0f + __expf(-x));
}

// ================= fused prep kernel (R11 layout — measured-good) =================
// [0,800)      nw3T 64x64-tile transpose
// [800,832)    ew2T 64x64-tile transpose (8 k-tiles x 4 n-tiles)
// [832,848)    wijT U-half tiles (2 k x 8 n)
// [848,864)    wijT V-half tiles (2 k x 8 n)
// [864,1120)   Zc = z @ W_z + eb1
// [1120,1376)  fused node MLP L1+L2 -> h2b
// [1376,1381)  ptab
#define TR3_B0   0
#define EW2_B0   800
#define WIU_B0   832
#define WIV_B0   848
#define ZC_B0    864
#define ND_B0    1120
#define PT_B0    1376
#define PREPK_NB 1381

__global__ __launch_bounds__(256) void k_prep_all(
    const float* __restrict__ nw3, ushort* __restrict__ nw3T,
    const float* __restrict__ ew1, const float* __restrict__ ew2,
    ushort* __restrict__ ew2T, ushort* __restrict__ wijT,
    const float* __restrict__ z, const float* __restrict__ eb1,
    float* __restrict__ Zc,
    const float* __restrict__ nw1, const float* __restrict__ nb1,
    const float* __restrict__ nw2, const float* __restrict__ nb2,
    ushort* __restrict__ h2b, int* __restrict__ ptab)
{
    __shared__ float smem[64 * 65];
    int b = blockIdx.x;
    int tid = threadIdx.x;
    int tx = tid & 63, ty = tid >> 6;   // 64 x 4

    if (b < EW2_B0) {
        // ---- nw3 transpose, 64x64 tiles (8 k-tiles x 100 n-tiles)
        int bb = b - TR3_B0;
        int k0 = (bb & 7) * 64;
        int n0 = (bb >> 3) * 64;
#pragma unroll
        for (int r = 0; r < 16; r++) {
            int row = r * 4 + ty;
            smem[row * 65 + tx] = nw3[(k0 + row) * NODE_OUT + n0 + tx];
        }
        __syncthreads();
#pragma unroll
        for (int c = 0; c < 16; c++) {
            int n = c * 4 + ty;
            nw3T[(size_t)(n0 + n) * HIDDEN + k0 + tx] = f2bf(smem[tx * 65 + n]);
        }
    } else if (b < WIU_B0) {
        // ---- ew2T[n][k] = ew2[k][n], tiled: ew2 is 512x256
        int bb = b - EW2_B0;
        int k0 = (bb >> 2) * 64;
        int n0 = (bb & 3) * 64;
#pragma unroll
        for (int r = 0; r < 16; r++) {
            int row = r * 4 + ty;
            smem[row * 65 + tx] = ew2[(k0 + row) * 256 + n0 + tx];
        }
        __syncthreads();
#pragma unroll
        for (int c = 0; c < 16; c++) {
            int n = c * 4 + ty;
            ew2T[(n0 + n) * HIDDEN + k0 + tx] = f2bf(smem[tx * 65 + n]);
        }
    } else if (b < WIV_B0) {
        // ---- wijT U-half: wijT[n][k] = ew1[256+k][n], n<512, k<128
        int bb = b - WIU_B0;
        int k0 = (bb >> 3) * 64;
        int n0 = (bb & 7) * 64;
#pragma unroll
        for (int r = 0; r < 16; r++) {
            int row = r * 4 + ty;
            smem[row * 65 + tx] = ew1[(256 + k0 + row) * 512 + n0 + tx];
        }
        __syncthreads();
#pragma unroll
        for (int c = 0; c < 16; c++) {
            int n = c * 4 + ty;
            wijT[(n0 + n) * NODE_F + k0 + tx] = f2bf(smem[tx * 65 + n]);
        }
    } else if (b < ZC_B0) {
        // ---- wijT V-half: wijT[512+n][k] = ew1[384+k][n], n<512, k<128
        int bb = b - WIV_B0;
        int k0 = (bb >> 3) * 64;
        int n0 = (bb & 7) * 64;
#pragma unroll
        for (int r = 0; r < 16; r++) {
            int row = r * 4 + ty;
            smem[row * 65 + tx] = ew1[(384 + k0 + row) * 512 + n0 + tx];
        }
        __syncthreads();
#pragma unroll
        for (int c = 0; c < 16; c++) {
            int n = c * 4 + ty;
            wijT[(512 + n0 + n) * NODE_F + k0 + tx] = f2bf(smem[tx * 65 + n]);
        }
    } else if (b < ND_B0) {
        // ---- Zc = z @ W_z + eb1
        int b2 = b - ZC_B0;
        int r = b2 >> 1, o = (b2 & 1) * 256 + tid;
        float* zs = smem;
        zs[tid] = z[r * LATENT + tid];
        __syncthreads();
        float acc = 0.f;
#pragma unroll 8
        for (int k = 0; k < LATENT; k++) acc += zs[k] * ew1[k * HIDDEN + o];
        Zc[r * HIDDEN + o] = acc + eb1[o];
    } else if (b < PT_B0) {
        // ---- fused node MLP L1+L2
        int b2 = b - ND_B0;
        int r = b2 >> 1, half = b2 & 1;
        float* zs = smem;            // 256 floats
        float* hs = smem + 256;      // 512 floats
        zs[tid] = z[r * LATENT + tid];
        __syncthreads();
        float a0 = 0.f, a1 = 0.f;
#pragma unroll 8
        for (int k = 0; k < LATENT; k++) {
            float zk = zs[k];
            a0 += zk * nw1[k * HIDDEN + tid];
            a1 += zk * nw1[k * HIDDEN + tid + 256];
        }
        hs[tid]       = fmaxf(a0 + nb1[tid], 0.f);
        hs[tid + 256] = fmaxf(a1 + nb1[tid + 256], 0.f);
        __syncthreads();
        int o = half * 256 + tid;
        float acc = 0.f;
#pragma unroll 8
        for (int k = 0; k < HIDDEN; k++) acc += hs[k] * nw2[k * HIDDEN + o];
        acc += nb2[o];
        h2b[r * HIDDEN + o] = f2bf(fmaxf(acc, 0.f));
    } else {
        int p = (b - PT_B0) * 256 + tid;
        if (p < NPAIRS) {
            int i = 0, off = 0;
            while (p - off >= MAX_NODES - 1 - i) { off += MAX_NODES - 1 - i; ++i; }
            int j = i + 1 + (p - off);
            ptab[p] = (i << 8) | j;
        }
    }
}

// ---------------- R15: fused node-L3 + UV kernel
// grid 200 = 50 nodes x 4 batch-quarters(32 rows). 256 threads = 4 waves.
// Phase 1: C1[32 rows][128 feats] = h2b @ nw3T-slice (K=512); sigmoid ->
//          node_probs (global), raw bf16 -> nf_lds (LDS only — nf never
//          touches HBM).
// Phase 2: UV rows (b*50+nd) = nf_lds @ wijT (K=128), A held in 32 VGPRs.
__global__ __launch_bounds__(256, 2) void k_node_uv(
    const ushort* __restrict__ h2b, const ushort* __restrict__ nw3T,
    const float* __restrict__ nb3, const ushort* __restrict__ wijT,
    float* __restrict__ node_probs, ushort* __restrict__ UV)
{
    __shared__ ushort nf_lds[32][132];   // +4 pad: row stride 264B = 66 dwords,
                                         // 66 mod 32 = 2 -> 16 rows hit 16 banks
    int tid = threadIdx.x;
    int wave = tid >> 6, lane = tid & 63;
    int m16 = lane & 15, quad = lane >> 4;
    int kk0 = quad * 8;

    int nd = blockIdx.x >> 2;            // node 0..49
    int m0 = (blockIdx.x & 3) * 32;      // batch-row quarter
    int colbase = nd * 128 + wave * 32;  // phase-1 cols for this wave

    // ---- phase 1: node layer-3 tile (32 rows x 32 cols per wave)
    float4v acc[2][2];
#pragma unroll
    for (int mf = 0; mf < 2; mf++)
#pragma unroll
        for (int nt = 0; nt < 2; nt++) acc[mf][nt] = (float4v)(0.f);

    const ushort* b0 = nw3T + (size_t)(colbase + m16) * HIDDEN;
    const ushort* b1 = nw3T + (size_t)(colbase + 16 + m16) * HIDDEN;
    const ushort* a0p = h2b + (m0 + m16) * HIDDEN;
    const ushort* a1p = h2b + (m0 + 16 + m16) * HIDDEN;
#pragma unroll
    for (int it = 0; it < 16; ++it) {
        int kk = it * 32 + kk0;
        short8 bf0 = *(const short8*)(b0 + kk);
        short8 bf1 = *(const short8*)(b1 + kk);
        short8 af0 = *(const short8*)(a0p + kk);
        short8 af1 = *(const short8*)(a1p + kk);
        acc[0][0] = __builtin_amdgcn_mfma_f32_16x16x32_bf16(af0, bf0, acc[0][0], 0, 0, 0);
        acc[0][1] = __builtin_amdgcn_mfma_f32_16x16x32_bf16(af0, bf1, acc[0][1], 0, 0, 0);
        acc[1][0] = __builtin_amdgcn_mfma_f32_16x16x32_bf16(af1, bf0, acc[1][0], 0, 0, 0);
        acc[1][1] = __builtin_amdgcn_mfma_f32_16x16x32_bf16(af1, bf1, acc[1][1], 0, 0, 0);
    }
    float bias0 = nb3[colbase + m16];
    float bias1 = nb3[colbase + 16 + m16];
#pragma unroll
    for (int mf = 0; mf < 2; mf++)
#pragma unroll
        for (int nt = 0; nt < 2; nt++) {
            float bias = nt ? bias1 : bias0;
            int colL = wave * 32 + nt * 16 + m16;          // 0..127 local feat
#pragma unroll
            for (int t = 0; t < 4; t++) {
                int rowL = mf * 16 + quad * 4 + t;         // 0..31 local batch
                float v = acc[mf][nt][t] + bias;
                node_probs[(size_t)(m0 + rowL) * NODE_OUT + nd * 128 + colL] = sigmoidf(v);
                nf_lds[rowL][colL] = f2bf(v);
            }
        }
    __syncthreads();

    // ---- phase 2: UV tile (32 rows x 256 cols per wave, K=128)
    short8 Areg[2][4];
#pragma unroll
    for (int mf = 0; mf < 2; mf++)
#pragma unroll
        for (int ks = 0; ks < 4; ks++)
            Areg[mf][ks] = *(const short8*)&nf_lds[mf * 16 + m16][ks * 32 + kk0];

#pragma unroll
    for (int nfi = 0; nfi < 16; ++nfi) {
        int colg = wave * 256 + nfi * 16 + m16;            // 0..1023
        const ushort* bp = wijT + colg * NODE_F + kk0;
        float4v u0 = (float4v)(0.f), u1 = (float4v)(0.f);
#pragma unroll
        for (int ks = 0; ks < 4; ks++) {
            short8 bfr = *(const short8*)(bp + ks * 32);
            u0 = __builtin_amdgcn_mfma_f32_16x16x32_bf16(Areg[0][ks], bfr, u0, 0, 0, 0);
            u1 = __builtin_amdgcn_mfma_f32_16x16x32_bf16(Areg[1][ks], bfr, u1, 0, 0, 0);
        }
#pragma unroll
        for (int t = 0; t < 4; t++) {
            int r0g = m0 + quad * 4 + t;
            UV[(size_t)(r0g * MAX_NODES + nd) * 1024 + colg]        = f2bf(u0[t]);
            UV[(size_t)((r0g + 16) * MAX_NODES + nd) * 1024 + colg] = f2bf(u1[t]);
        }
    }
}

// ---------------- fused edge, persistent-B, TPB=10, grid 256 (1 block/CU)
// R12 (measured 70.1 µs): single barrier per tile (part double-buffered,
// out-write deferred one tile), reduce uses only shfl_xor 1,2 (DPP).
__global__ __launch_bounds__(512, 2) void k_edge8(
    const float* __restrict__ Zc, const ushort* __restrict__ UV,
    const ushort* __restrict__ ew2T, const float* __restrict__ ew3,
    const float* __restrict__ eb2, const float* __restrict__ eb3,
    const int* __restrict__ ptab, float* __restrict__ out_edges)
{
    __shared__ __align__(16) ushort h1[2][MTILE][HIDDEN + 8]; // 133,120 B
    __shared__ float part[2][MTILE][33];                      //  16,896 B
    __shared__ int uo5[TPB][MTILE], vo5[TPB][MTILE];          //   5,120 B
    // total 155,136 B <= 160 KiB -> 1 block/CU

    int tid  = threadIdx.x;
    int blk  = blockIdx.x;
    int b    = blk >> 1;
    int ti0  = (blk & 1) * TPB;

    if (tid < MTILE) {
#pragma unroll
        for (int t = 0; t < TPB; t++) {
            int p = (ti0 + t) * MTILE + tid;
            if (p >= NPAIRS) p = NPAIRS - 1;
            int ij = ptab[p];
            uo5[t][tid] = (b * MAX_NODES + (ij >> 8)) * 1024;
            vo5[t][tid] = (b * MAX_NODES + (ij & 255)) * 1024 + 512;
        }
    }

    int wave = tid >> 6, lane = tid & 63;
    int m16 = lane & 15, quad = lane >> 4;
    int c8 = lane * 8;
    int kk0 = quad * 8;

    float4v zA = *(const float4v*)(Zc + b * HIDDEN + c8);
    float4v zB = *(const float4v*)(Zc + b * HIDDEN + c8 + 4);

    const ushort* bb0 = ew2T + (wave * 32 + m16) * HIDDEN;
    const ushort* bb1 = ew2T + (wave * 32 + 16 + m16) * HIDDEN;
    short8 Breg[16][2];
#pragma unroll
    for (int kc = 0; kc < 16; kc++) {
        Breg[kc][0] = *(const short8*)(bb0 + kc * 32 + kk0);
        Breg[kc][1] = *(const short8*)(bb1 + kc * 32 + kk0);
    }
    float eb2v[2], ew3v[2];
    eb2v[0] = eb2[wave * 32 + m16];      eb2v[1] = eb2[wave * 32 + 16 + m16];
    ew3v[0] = ew3[wave * 32 + m16];      ew3v[1] = ew3[wave * 32 + 16 + m16];

    __syncthreads();

    // ---- prologue: build tile 0 into h1[0]
#pragma unroll
    for (int rr = 0; rr < 8; rr++) {
        int r = wave * 8 + rr;
        short8 u8 = *(const short8*)(UV + uo5[0][r] + c8);
        short8 v8 = *(const short8*)(UV + vo5[0][r] + c8);
        S8U hh;
#pragma unroll
        for (int e2 = 0; e2 < 4; e2++) {
            float z0 = (e2 < 2) ? zA[e2 * 2] : zB[e2 * 2 - 4];
            float z1 = (e2 < 2) ? zA[e2 * 2 + 1] : zB[e2 * 2 - 3];
            float f0 = fmaxf(z0 + bf2f((ushort)u8[e2 * 2]) + bf2f((ushort)v8[e2 * 2]), 0.f);
            float f1 = fmaxf(z1 + bf2f((ushort)u8[e2 * 2 + 1]) + bf2f((ushort)v8[e2 * 2 + 1]), 0.f);
            hh.u[e2] = pk_bf16(f0, f1);
        }
        *(short8*)&h1[0][r][c8] = hh.s;
    }
    __syncthreads();

    for (int t = 0; t < TPB; t++) {
        int cur = t & 1, nxt = cur ^ 1;
        bool hasNext = (t + 1 < TPB);

        // ---- deferred edge-output write for tile t-1 (overlaps other waves' MFMA)
        if (t > 0 && tid < MTILE) {
            int p = (ti0 + t - 1) * MTILE + tid;
            if (p < NPAIRS) {
                float v = eb3[0];
#pragma unroll
                for (int w = 0; w < 32; w++) v += part[nxt][tid][w];
                out_edges[b * NPAIRS + p] = sigmoidf(v);
            }
        }

        float4v acc2[4][2];
#pragma unroll
        for (int mt = 0; mt < 4; mt++)
#pragma unroll
            for (int nt = 0; nt < 2; nt++) acc2[mt][nt] = (float4v)(0.f);

        short8 uu[4], vv[4];
        if (hasNext) {
#pragma unroll
            for (int rr = 0; rr < 4; rr++) {
                int r = wave * 8 + rr;
                uu[rr] = *(const short8*)(UV + uo5[t + 1][r] + c8);
                vv[rr] = *(const short8*)(UV + vo5[t + 1][r] + c8);
            }
        }
#pragma unroll
        for (int it = 0; it < 8; ++it) {
            int kk = it * 32 + kk0;
            short8 a0 = *(const short8*)&h1[cur][m16][kk];
            short8 a1 = *(const short8*)&h1[cur][16 + m16][kk];
            short8 a2 = *(const short8*)&h1[cur][32 + m16][kk];
            short8 a3 = *(const short8*)&h1[cur][48 + m16][kk];
            acc2[0][0] = __builtin_amdgcn_mfma_f32_16x16x32_bf16(a0, Breg[it][0], acc2[0][0], 0, 0, 0);
            acc2[1][0] = __builtin_amdgcn_mfma_f32_16x16x32_bf16(a1, Breg[it][0], acc2[1][0], 0, 0, 0);
            acc2[2][0] = __builtin_amdgcn_mfma_f32_16x16x32_bf16(a2, Breg[it][0], acc2[2][0], 0, 0, 0);
            acc2[3][0] = __builtin_amdgcn_mfma_f32_16x16x32_bf16(a3, Breg[it][0], acc2[3][0], 0, 0, 0);
            acc2[0][1] = __builtin_amdgcn_mfma_f32_16x16x32_bf16(a0, Breg[it][1], acc2[0][1], 0, 0, 0);
            acc2[1][1] = __builtin_amdgcn_mfma_f32_16x16x32_bf16(a1, Breg[it][1], acc2[1][1], 0, 0, 0);
            acc2[2][1] = __builtin_amdgcn_mfma_f32_16x16x32_bf16(a2, Breg[it][1], acc2[2][1], 0, 0, 0);
            acc2[3][1] = __builtin_amdgcn_mfma_f32_16x16x32_bf16(a3, Breg[it][1], acc2[3][1], 0, 0, 0);
        }
        if (hasNext) {
#pragma unroll
            for (int rr = 0; rr < 4; rr++) {
                int r = wave * 8 + rr;
                S8U hh;
#pragma unroll
                for (int e2 = 0; e2 < 4; e2++) {
                    float z0 = (e2 < 2) ? zA[e2 * 2] : zB[e2 * 2 - 4];
                    float z1 = (e2 < 2) ? zA[e2 * 2 + 1] : zB[e2 * 2 - 3];
                    float f0 = fmaxf(z0 + bf2f((ushort)uu[rr][e2 * 2]) + bf2f((ushort)vv[rr][e2 * 2]), 0.f);
                    float f1 = fmaxf(z1 + bf2f((ushort)uu[rr][e2 * 2 + 1]) + bf2f((ushort)vv[rr][e2 * 2 + 1]), 0.f);
                    hh.u[e2] = pk_bf16(f0, f1);
                }
                *(short8*)&h1[nxt][r][c8] = hh.s;
            }
#pragma unroll
            for (int rr = 0; rr < 4; rr++) {
                int r = wave * 8 + 4 + rr;
                uu[rr] = *(const short8*)(UV + uo5[t + 1][r] + c8);
                vv[rr] = *(const short8*)(UV + vo5[t + 1][r] + c8);
            }
        }
#pragma unroll
        for (int it = 8; it < 16; ++it) {
            int kk = it * 32 + kk0;
            short8 a0 = *(const short8*)&h1[cur][m16][kk];
            short8 a1 = *(const short8*)&h1[cur][16 + m16][kk];
            short8 a2 = *(const short8*)&h1[cur][32 + m16][kk];
            short8 a3 = *(const short8*)&h1[cur][48 + m16][kk];
            acc2[0][0] = __builtin_amdgcn_mfma_f32_16x16x32_bf16(a0, Breg[it][0], acc2[0][0], 0, 0, 0);
            acc2[1][0] = __builtin_amdgcn_mfma_f32_16x16x32_bf16(a1, Breg[it][0], acc2[1][0], 0, 0, 0);
            acc2[2][0] = __builtin_amdgcn_mfma_f32_16x16x32_bf16(a2, Breg[it][0], acc2[2][0], 0, 0, 0);
            acc2[3][0] = __builtin_amdgcn_mfma_f32_16x16x32_bf16(a3, Breg[it][0], acc2[3][0], 0, 0, 0);
            acc2[0][1] = __builtin_amdgcn_mfma_f32_16x16x32_bf16(a0, Breg[it][1], acc2[0][1], 0, 0, 0);
            acc2[1][1] = __builtin_amdgcn_mfma_f32_16x16x32_bf16(a1, Breg[it][1], acc2[1][1], 0, 0, 0);
            acc2[2][1] = __builtin_amdgcn_mfma_f32_16x16x32_bf16(a2, Breg[it][1], acc2[2][1], 0, 0, 0);
            acc2[3][1] = __builtin_amdgcn_mfma_f32_16x16x32_bf16(a3, Breg[it][1], acc2[3][1], 0, 0, 0);
        }
        if (hasNext) {
#pragma unroll
            for (int rr = 0; rr < 4; rr++) {
                int r = wave * 8 + 4 + rr;
                S8U hh;
#pragma unroll
                for (int e2 = 0; e2 < 4; e2++) {
                    float z0 = (e2 < 2) ? zA[e2 * 2] : zB[e2 * 2 - 4];
                    float z1 = (e2 < 2) ? zA[e2 * 2 + 1] : zB[e2 * 2 - 3];
                    float f0 = fmaxf(z0 + bf2f((ushort)uu[rr][e2 * 2]) + bf2f((ushort)vv[rr][e2 * 2]), 0.f);
                    float f1 = fmaxf(z1 + bf2f((ushort)uu[rr][e2 * 2 + 1]) + bf2f((ushort)vv[rr][e2 * 2 + 1]), 0.f);
                    hh.u[e2] = pk_bf16(f0, f1);
                }
                *(short8*)&h1[nxt][r][c8] = hh.s;
            }
        }

        // ---- reduce: xor1,xor2 only (DPP); 4 partials / 16-lane group -> part[cur]
#pragma unroll
        for (int mt = 0; mt < 4; mt++)
#pragma unroll
            for (int tt = 0; tt < 4; tt++) {
                float s = 0.f;
#pragma unroll
                for (int nt = 0; nt < 2; nt++)
                    s += fmaxf(acc2[mt][nt][tt] + eb2v[nt], 0.f) * ew3v[nt];
                s += __shfl_xor(s, 1);
                s += __shfl_xor(s, 2);
                if ((m16 & 3) == 0)
                    part[cur][mt * 16 + quad * 4 + tt][wave * 4 + (m16 >> 2)] = s;
            }
        __syncthreads();   // single barrier/tile: orders h1 phase flip + part publish
    }

    // ---- tail: edge-output write for the last tile
    if (tid < MTILE) {
        int p = (ti0 + TPB - 1) * MTILE + tid;
        if (p < NPAIRS) {
            float v = eb3[0];
#pragma unroll
            for (int w = 0; w < 32; w++) v += part[(TPB - 1) & 1][tid][w];
            out_edges[b * NPAIRS + p] = sigmoidf(v);
        }
    }
}

extern "C" void kernel_launch(void* const* d_in, const int* in_sizes, int n_in,
                              void* d_out, int out_size, void* d_ws, size_t ws_size,
                              hipStream_t stream) {
    const float* z   = (const float*)d_in[0];
    const float* nw1 = (const float*)d_in[1];
    const float* nb1 = (const float*)d_in[2];
    const float* nw2 = (const float*)d_in[3];
    const float* nb2 = (const float*)d_in[4];
    const float* nw3 = (const float*)d_in[5];
    const float* nb3 = (const float*)d_in[6];
    const float* ew1 = (const float*)d_in[7];
    const float* eb1 = (const float*)d_in[8];
    const float* ew2 = (const float*)d_in[9];
    const float* eb2 = (const float*)d_in[10];
    const float* ew3 = (const float*)d_in[11];
    const float* eb3 = (const float*)d_in[12];

    char* ws = (char*)d_ws;
    int*    ptab = (int*)(ws);                       // 1225*4
    ushort* h2b  = (ushort*)(ws + 262144);           // 131072
    ushort* ew2T = (ushort*)(ws + 2031616);          // 262144
    ushort* wijT = (ushort*)(ws + 2293760);          // 262144
    ushort* nw3T = (ushort*)(ws + 2555904);          // 6553600
    float*  Zc   = (float*)(ws + 9109504);           // 262144
    ushort* UV   = (ushort*)(ws + 9371648);          // 13107200

    float* out_nodes = (float*)d_out;                // 128*6400
    float* out_edges = out_nodes + BATCH * NODE_OUT; // 128*1225

    k_prep_all<<<PREPK_NB, 256, 0, stream>>>(nw3, nw3T, ew1, ew2, ew2T, wijT,
                                             z, eb1, Zc, nw1, nb1, nw2, nb2,
                                             h2b, ptab);
    k_node_uv<<<200, 256, 0, stream>>>(h2b, nw3T, nb3, wijT, out_nodes, UV);
    k_edge8<<<NBLK, 512, 0, stream>>>(Zc, UV, ew2T, ew3, eb2, eb3, ptab, out_edges);
}

// Round 5
// 208.900 us; speedup vs baseline: 1.4095x; 1.0033x over previous
//
#include <hip/hip_runtime.h>
#include <hip/hip_bf16.h>
#include <math.h>

#define LATENT 256
#define HIDDEN 512
#define NODE_F 128
#define MAX_NODES 50
#define NPAIRS 1225        // 50*49/2
#define BATCH 128
#define NODE_OUT 6400      // MAX_NODES*NODE_F
#define MTILE 64           // edge rows per tile (R12-measured)
#define TPB 10             // tiles per block (20 tiles/batch = 2 blocks/batch)
#define NBLK 256           // edge grid (1 block/CU)

typedef __attribute__((ext_vector_type(8))) short short8;
typedef __attribute__((ext_vector_type(4))) float float4v;

union S8U { short8 s; unsigned int u[4]; };

__device__ __forceinline__ float bf2f(ushort u) {
    union { unsigned int i; float f; } v; v.i = ((unsigned int)u) << 16; return v.f;
}
__device__ __forceinline__ ushort f2bf(float f) {
    union { unsigned int i; float f; } v; v.f = f;
    unsigned int r = v.i + 0x7fffu + ((v.i >> 16) & 1u);   // RNE
    return (ushort)(r >> 16);
}
__device__ __forceinline__ unsigned int pk_bf16(float f0, float f1) {
    __hip_bfloat162 p = __float22bfloat162_rn(float2{f0, f1});   // v_cvt_pk_bf16_f32 (RNE)
    unsigned int w; __builtin_memcpy(&w, &p, 4); return w;
}
__device__ __forceinline__ float sigmoidf(float x) {
    return 1.0f / (1.0f + __expf(-x));
}

// ================= prep kernel (R16: nw3 transpose DELETED — node_uv reads
// nw3 f32 directly). Long-latency sections dispatch first.
// [0,256)    fused node MLP L1+L2 -> h2b
// [256,512)  Zc = z @ W_z + eb1
// [512,544)  ew2T 64x64-tile transpose (8 k-tiles x 4 n-tiles)
// [544,560)  wijT U-half tiles (2 k x 8 n)
// [560,576)  wijT V-half tiles (2 k x 8 n)
// [576,581)  ptab
#define ND_B0    0
#define ZC_B0    256
#define EW2_B0   512
#define WIU_B0   544
#define WIV_B0   560
#define PT_B0    576
#define PREPK_NB 581

__global__ __launch_bounds__(256) void k_prep_all(
    const float* __restrict__ ew1, const float* __restrict__ ew2,
    ushort* __restrict__ ew2T, ushort* __restrict__ wijT,
    const float* __restrict__ z, const float* __restrict__ eb1,
    float* __restrict__ Zc,
    const float* __restrict__ nw1, const float* __restrict__ nb1,
    const float* __restrict__ nw2, const float* __restrict__ nb2,
    ushort* __restrict__ h2b, int* __restrict__ ptab)
{
    __shared__ float smem[64 * 65];
    int b = blockIdx.x;
    int tid = threadIdx.x;
    int tx = tid & 63, ty = tid >> 6;   // 64 x 4

    if (b < ZC_B0) {
        // ---- fused node MLP L1+L2
        int b2 = b - ND_B0;
        int r = b2 >> 1, half = b2 & 1;
        float* zs = smem;            // 256 floats
        float* hs = smem + 256;      // 512 floats
        zs[tid] = z[r * LATENT + tid];
        __syncthreads();
        float a0 = 0.f, a1 = 0.f;
#pragma unroll 8
        for (int k = 0; k < LATENT; k++) {
            float zk = zs[k];
            a0 += zk * nw1[k * HIDDEN + tid];
            a1 += zk * nw1[k * HIDDEN + tid + 256];
        }
        hs[tid]       = fmaxf(a0 + nb1[tid], 0.f);
        hs[tid + 256] = fmaxf(a1 + nb1[tid + 256], 0.f);
        __syncthreads();
        int o = half * 256 + tid;
        float acc = 0.f;
#pragma unroll 8
        for (int k = 0; k < HIDDEN; k++) acc += hs[k] * nw2[k * HIDDEN + o];
        acc += nb2[o];
        h2b[r * HIDDEN + o] = f2bf(fmaxf(acc, 0.f));
    } else if (b < EW2_B0) {
        // ---- Zc = z @ W_z + eb1
        int b2 = b - ZC_B0;
        int r = b2 >> 1, o = (b2 & 1) * 256 + tid;
        float* zs = smem;
        zs[tid] = z[r * LATENT + tid];
        __syncthreads();
        float acc = 0.f;
#pragma unroll 8
        for (int k = 0; k < LATENT; k++) acc += zs[k] * ew1[k * HIDDEN + o];
        Zc[r * HIDDEN + o] = acc + eb1[o];
    } else if (b < WIU_B0) {
        // ---- ew2T[n][k] = ew2[k][n], tiled: ew2 is 512x256
        int bb = b - EW2_B0;
        int k0 = (bb >> 2) * 64;
        int n0 = (bb & 3) * 64;
#pragma unroll
        for (int r = 0; r < 16; r++) {
            int row = r * 4 + ty;
            smem[row * 65 + tx] = ew2[(k0 + row) * 256 + n0 + tx];
        }
        __syncthreads();
#pragma unroll
        for (int c = 0; c < 16; c++) {
            int n = c * 4 + ty;
            ew2T[(n0 + n) * HIDDEN + k0 + tx] = f2bf(smem[tx * 65 + n]);
        }
    } else if (b < WIV_B0) {
        // ---- wijT U-half: wijT[n][k] = ew1[256+k][n], n<512, k<128
        int bb = b - WIU_B0;
        int k0 = (bb >> 3) * 64;
        int n0 = (bb & 7) * 64;
#pragma unroll
        for (int r = 0; r < 16; r++) {
            int row = r * 4 + ty;
            smem[row * 65 + tx] = ew1[(256 + k0 + row) * 512 + n0 + tx];
        }
        __syncthreads();
#pragma unroll
        for (int c = 0; c < 16; c++) {
            int n = c * 4 + ty;
            wijT[(n0 + n) * NODE_F + k0 + tx] = f2bf(smem[tx * 65 + n]);
        }
    } else if (b < PT_B0) {
        // ---- wijT V-half: wijT[512+n][k] = ew1[384+k][n], n<512, k<128
        int bb = b - WIV_B0;
        int k0 = (bb >> 3) * 64;
        int n0 = (bb & 7) * 64;
#pragma unroll
        for (int r = 0; r < 16; r++) {
            int row = r * 4 + ty;
            smem[row * 65 + tx] = ew1[(384 + k0 + row) * 512 + n0 + tx];
        }
        __syncthreads();
#pragma unroll
        for (int c = 0; c < 16; c++) {
            int n = c * 4 + ty;
            wijT[(512 + n0 + n) * NODE_F + k0 + tx] = f2bf(smem[tx * 65 + n]);
        }
    } else {
        int p = (b - PT_B0) * 256 + tid;
        if (p < NPAIRS) {
            int i = 0, off = 0;
            while (p - off >= MAX_NODES - 1 - i) { off += MAX_NODES - 1 - i; ++i; }
            int j = i + 1 + (p - off);
            ptab[p] = (i << 8) | j;
        }
    }
}

// ---------------- R16: fused node-L3 + UV kernel, direct-nw3 B-loads
// grid 200 = 50 nodes x 4 batch-quarters(32 rows). 256 threads = 4 waves.
// Phase 1: B-fragments built on the fly from f32 nw3 column-slices
//          (16 lanes x consecutive cols -> 64B coalesced segments per k-row;
//          cvt_pk RNE == prep's f2bf, numerics identical to nw3T path).
// Phase 2: UV rows = nf_lds @ wijT (K=128), A held in 32 VGPRs.
__global__ __launch_bounds__(256, 2) void k_node_uv(
    const ushort* __restrict__ h2b, const float* __restrict__ nw3,
    const float* __restrict__ nb3, const ushort* __restrict__ wijT,
    float* __restrict__ node_probs, ushort* __restrict__ UV)
{
    __shared__ ushort nf_lds[32][132];
    int tid = threadIdx.x;
    int wave = tid >> 6, lane = tid & 63;
    int m16 = lane & 15, quad = lane >> 4;
    int kk0 = quad * 8;

    int nd = blockIdx.x >> 2;            // node 0..49
    int m0 = (blockIdx.x & 3) * 32;      // batch-row quarter
    int colbase = nd * 128 + wave * 32;  // phase-1 cols for this wave

    // ---- phase 1: node layer-3 tile (32 rows x 32 cols per wave)
    float4v acc[2][2];
#pragma unroll
    for (int mf = 0; mf < 2; mf++)
#pragma unroll
        for (int nt = 0; nt < 2; nt++) acc[mf][nt] = (float4v)(0.f);

    const float* bcol0 = nw3 + colbase + m16;         // + k*NODE_OUT
    const float* bcol1 = nw3 + colbase + 16 + m16;
    const ushort* a0p = h2b + (m0 + m16) * HIDDEN;
    const ushort* a1p = h2b + (m0 + 16 + m16) * HIDDEN;
#pragma unroll 4
    for (int it = 0; it < 16; ++it) {
        int kk = it * 32 + kk0;
        const float* bp0 = bcol0 + (size_t)kk * NODE_OUT;
        const float* bp1 = bcol1 + (size_t)kk * NODE_OUT;
        S8U b0u, b1u;
#pragma unroll
        for (int j = 0; j < 4; j++) {
            b0u.u[j] = pk_bf16(bp0[(2 * j) * NODE_OUT], bp0[(2 * j + 1) * NODE_OUT]);
            b1u.u[j] = pk_bf16(bp1[(2 * j) * NODE_OUT], bp1[(2 * j + 1) * NODE_OUT]);
        }
        short8 af0 = *(const short8*)(a0p + kk);
        short8 af1 = *(const short8*)(a1p + kk);
        acc[0][0] = __builtin_amdgcn_mfma_f32_16x16x32_bf16(af0, b0u.s, acc[0][0], 0, 0, 0);
        acc[0][1] = __builtin_amdgcn_mfma_f32_16x16x32_bf16(af0, b1u.s, acc[0][1], 0, 0, 0);
        acc[1][0] = __builtin_amdgcn_mfma_f32_16x16x32_bf16(af1, b0u.s, acc[1][0], 0, 0, 0);
        acc[1][1] = __builtin_amdgcn_mfma_f32_16x16x32_bf16(af1, b1u.s, acc[1][1], 0, 0, 0);
    }
    float bias0 = nb3[colbase + m16];
    float bias1 = nb3[colbase + 16 + m16];
#pragma unroll
    for (int mf = 0; mf < 2; mf++)
#pragma unroll
        for (int nt = 0; nt < 2; nt++) {
            float bias = nt ? bias1 : bias0;
            int colL = wave * 32 + nt * 16 + m16;          // 0..127 local feat
#pragma unroll
            for (int t = 0; t < 4; t++) {
                int rowL = mf * 16 + quad * 4 + t;         // 0..31 local batch
                float v = acc[mf][nt][t] + bias;
                node_probs[(size_t)(m0 + rowL) * NODE_OUT + nd * 128 + colL] = sigmoidf(v);
                nf_lds[rowL][colL] = f2bf(v);
            }
        }
    __syncthreads();

    // ---- phase 2: UV tile (32 rows x 256 cols per wave, K=128)
    short8 Areg[2][4];
#pragma unroll
    for (int mf = 0; mf < 2; mf++)
#pragma unroll
        for (int ks = 0; ks < 4; ks++)
            Areg[mf][ks] = *(const short8*)&nf_lds[mf * 16 + m16][ks * 32 + kk0];

#pragma unroll
    for (int nfi = 0; nfi < 16; ++nfi) {
        int colg = wave * 256 + nfi * 16 + m16;            // 0..1023
        const ushort* bp = wijT + colg * NODE_F + kk0;
        float4v u0 = (float4v)(0.f), u1 = (float4v)(0.f);
#pragma unroll
        for (int ks = 0; ks < 4; ks++) {
            short8 bfr = *(const short8*)(bp + ks * 32);
            u0 = __builtin_amdgcn_mfma_f32_16x16x32_bf16(Areg[0][ks], bfr, u0, 0, 0, 0);
            u1 = __builtin_amdgcn_mfma_f32_16x16x32_bf16(Areg[1][ks], bfr, u1, 0, 0, 0);
        }
#pragma unroll
        for (int t = 0; t < 4; t++) {
            int r0g = m0 + quad * 4 + t;
            UV[(size_t)(r0g * MAX_NODES + nd) * 1024 + colg]        = f2bf(u0[t]);
            UV[(size_t)((r0g + 16) * MAX_NODES + nd) * 1024 + colg] = f2bf(u1[t]);
        }
    }
}

// ---------------- fused edge, persistent-B, TPB=10, grid 256 (1 block/CU)
// R12 (measured 70.1 µs on fast chip): single barrier per tile (part
// double-buffered, out-write deferred one tile), DPP-only reduce.
// NOTE: the 5.24M LDS conflicts are structural — b128 A-reads force row
// stride ≡ 0 mod 4 dwords, so 64 lanes land on 8 bank-groups (8-way) for
// ANY pad/swizzle. Occupancy pinned at 2 waves/SIMD by Breg=128 VGPR.
__global__ __launch_bounds__(512, 2) void k_edge8(
    const float* __restrict__ Zc, const ushort* __restrict__ UV,
    const ushort* __restrict__ ew2T, const float* __restrict__ ew3,
    const float* __restrict__ eb2, const float* __restrict__ eb3,
    const int* __restrict__ ptab, float* __restrict__ out_edges)
{
    __shared__ __align__(16) ushort h1[2][MTILE][HIDDEN + 8]; // 133,120 B
    __shared__ float part[2][MTILE][33];                      //  16,896 B
    __shared__ int uo5[TPB][MTILE], vo5[TPB][MTILE];          //   5,120 B

    int tid  = threadIdx.x;
    int blk  = blockIdx.x;
    int b    = blk >> 1;
    int ti0  = (blk & 1) * TPB;

    if (tid < MTILE) {
#pragma unroll
        for (int t = 0; t < TPB; t++) {
            int p = (ti0 + t) * MTILE + tid;
            if (p >= NPAIRS) p = NPAIRS - 1;
            int ij = ptab[p];
            uo5[t][tid] = (b * MAX_NODES + (ij >> 8)) * 1024;
            vo5[t][tid] = (b * MAX_NODES + (ij & 255)) * 1024 + 512;
        }
    }

    int wave = tid >> 6, lane = tid & 63;
    int m16 = lane & 15, quad = lane >> 4;
    int c8 = lane * 8;
    int kk0 = quad * 8;

    float4v zA = *(const float4v*)(Zc + b * HIDDEN + c8);
    float4v zB = *(const float4v*)(Zc + b * HIDDEN + c8 + 4);

    const ushort* bb0 = ew2T + (wave * 32 + m16) * HIDDEN;
    const ushort* bb1 = ew2T + (wave * 32 + 16 + m16) * HIDDEN;
    short8 Breg[16][2];
#pragma unroll
    for (int kc = 0; kc < 16; kc++) {
        Breg[kc][0] = *(const short8*)(bb0 + kc * 32 + kk0);
        Breg[kc][1] = *(const short8*)(bb1 + kc * 32 + kk0);
    }
    float eb2v[2], ew3v[2];
    eb2v[0] = eb2[wave * 32 + m16];      eb2v[1] = eb2[wave * 32 + 16 + m16];
    ew3v[0] = ew3[wave * 32 + m16];      ew3v[1] = ew3[wave * 32 + 16 + m16];

    __syncthreads();

    // ---- prologue: build tile 0 into h1[0]
#pragma unroll
    for (int rr = 0; rr < 8; rr++) {
        int r = wave * 8 + rr;
        short8 u8 = *(const short8*)(UV + uo5[0][r] + c8);
        short8 v8 = *(const short8*)(UV + vo5[0][r] + c8);
        S8U hh;
#pragma unroll
        for (int e2 = 0; e2 < 4; e2++) {
            float z0 = (e2 < 2) ? zA[e2 * 2] : zB[e2 * 2 - 4];
            float z1 = (e2 < 2) ? zA[e2 * 2 + 1] : zB[e2 * 2 - 3];
            float f0 = fmaxf(z0 + bf2f((ushort)u8[e2 * 2]) + bf2f((ushort)v8[e2 * 2]), 0.f);
            float f1 = fmaxf(z1 + bf2f((ushort)u8[e2 * 2 + 1]) + bf2f((ushort)v8[e2 * 2 + 1]), 0.f);
            hh.u[e2] = pk_bf16(f0, f1);
        }
        *(short8*)&h1[0][r][c8] = hh.s;
    }
    __syncthreads();

    for (int t = 0; t < TPB; t++) {
        int cur = t & 1, nxt = cur ^ 1;
        bool hasNext = (t + 1 < TPB);

        // ---- deferred edge-output write for tile t-1 (overlaps other waves' MFMA)
        if (t > 0 && tid < MTILE) {
            int p = (ti0 + t - 1) * MTILE + tid;
            if (p < NPAIRS) {
                float v = eb3[0];
#pragma unroll
                for (int w = 0; w < 32; w++) v += part[nxt][tid][w];
                out_edges[b * NPAIRS + p] = sigmoidf(v);
            }
        }

        float4v acc2[4][2];
#pragma unroll
        for (int mt = 0; mt < 4; mt++)
#pragma unroll
            for (int nt = 0; nt < 2; nt++) acc2[mt][nt] = (float4v)(0.f);

        short8 uu[4], vv[4];
        if (hasNext) {
#pragma unroll
            for (int rr = 0; rr < 4; rr++) {
                int r = wave * 8 + rr;
                uu[rr] = *(const short8*)(UV + uo5[t + 1][r] + c8);
                vv[rr] = *(const short8*)(UV + vo5[t + 1][r] + c8);
            }
        }
#pragma unroll
        for (int it = 0; it < 8; ++it) {
            int kk = it * 32 + kk0;
            short8 a0 = *(const short8*)&h1[cur][m16][kk];
            short8 a1 = *(const short8*)&h1[cur][16 + m16][kk];
            short8 a2 = *(const short8*)&h1[cur][32 + m16][kk];
            short8 a3 = *(const short8*)&h1[cur][48 + m16][kk];
            acc2[0][0] = __builtin_amdgcn_mfma_f32_16x16x32_bf16(a0, Breg[it][0], acc2[0][0], 0, 0, 0);
            acc2[1][0] = __builtin_amdgcn_mfma_f32_16x16x32_bf16(a1, Breg[it][0], acc2[1][0], 0, 0, 0);
            acc2[2][0] = __builtin_amdgcn_mfma_f32_16x16x32_bf16(a2, Breg[it][0], acc2[2][0], 0, 0, 0);
            acc2[3][0] = __builtin_amdgcn_mfma_f32_16x16x32_bf16(a3, Breg[it][0], acc2[3][0], 0, 0, 0);
            acc2[0][1] = __builtin_amdgcn_mfma_f32_16x16x32_bf16(a0, Breg[it][1], acc2[0][1], 0, 0, 0);
            acc2[1][1] = __builtin_amdgcn_mfma_f32_16x16x32_bf16(a1, Breg[it][1], acc2[1][1], 0, 0, 0);
            acc2[2][1] = __builtin_amdgcn_mfma_f32_16x16x32_bf16(a2, Breg[it][1], acc2[2][1], 0, 0, 0);
            acc2[3][1] = __builtin_amdgcn_mfma_f32_16x16x32_bf16(a3, Breg[it][1], acc2[3][1], 0, 0, 0);
        }
        if (hasNext) {
#pragma unroll
            for (int rr = 0; rr < 4; rr++) {
                int r = wave * 8 + rr;
                S8U hh;
#pragma unroll
                for (int e2 = 0; e2 < 4; e2++) {
                    float z0 = (e2 < 2) ? zA[e2 * 2] : zB[e2 * 2 - 4];
                    float z1 = (e2 < 2) ? zA[e2 * 2 + 1] : zB[e2 * 2 - 3];
                    float f0 = fmaxf(z0 + bf2f((ushort)uu[rr][e2 * 2]) + bf2f((ushort)vv[rr][e2 * 2]), 0.f);
                    float f1 = fmaxf(z1 + bf2f((ushort)uu[rr][e2 * 2 + 1]) + bf2f((ushort)vv[rr][e2 * 2 + 1]), 0.f);
                    hh.u[e2] = pk_bf16(f0, f1);
                }
                *(short8*)&h1[nxt][r][c8] = hh.s;
            }
#pragma unroll
            for (int rr = 0; rr < 4; rr++) {
                int r = wave * 8 + 4 + rr;
                uu[rr] = *(const short8*)(UV + uo5[t + 1][r] + c8);
                vv[rr] = *(const short8*)(UV + vo5[t + 1][r] + c8);
            }
        }
#pragma unroll
        for (int it = 8; it < 16; ++it) {
            int kk = it * 32 + kk0;
            short8 a0 = *(const short8*)&h1[cur][m16][kk];
            short8 a1 = *(const short8*)&h1[cur][16 + m16][kk];
            short8 a2 = *(const short8*)&h1[cur][32 + m16][kk];
            short8 a3 = *(const short8*)&h1[cur][48 + m16][kk];
            acc2[0][0] = __builtin_amdgcn_mfma_f32_16x16x32_bf16(a0, Breg[it][0], acc2[0][0], 0, 0, 0);
            acc2[1][0] = __builtin_amdgcn_mfma_f32_16x16x32_bf16(a1, Breg[it][0], acc2[1][0], 0, 0, 0);
            acc2[2][0] = __builtin_amdgcn_mfma_f32_16x16x32_bf16(a2, Breg[it][0], acc2[2][0], 0, 0, 0);
            acc2[3][0] = __builtin_amdgcn_mfma_f32_16x16x32_bf16(a3, Breg[it][0], acc2[3][0], 0, 0, 0);
            acc2[0][1] = __builtin_amdgcn_mfma_f32_16x16x32_bf16(a0, Breg[it][1], acc2[0][1], 0, 0, 0);
            acc2[1][1] = __builtin_amdgcn_mfma_f32_16x16x32_bf16(a1, Breg[it][1], acc2[1][1], 0, 0, 0);
            acc2[2][1] = __builtin_amdgcn_mfma_f32_16x16x32_bf16(a2, Breg[it][1], acc2[2][1], 0, 0, 0);
            acc2[3][1] = __builtin_amdgcn_mfma_f32_16x16x32_bf16(a3, Breg[it][1], acc2[3][1], 0, 0, 0);
        }
        if (hasNext) {
#pragma unroll
            for (int rr = 0; rr < 4; rr++) {
                int r = wave * 8 + 4 + rr;
                S8U hh;
#pragma unroll
                for (int e2 = 0; e2 < 4; e2++) {
                    float z0 = (e2 < 2) ? zA[e2 * 2] : zB[e2 * 2 - 4];
                    float z1 = (e2 < 2) ? zA[e2 * 2 + 1] : zB[e2 * 2 - 3];
                    float f0 = fmaxf(z0 + bf2f((ushort)uu[rr][e2 * 2]) + bf2f((ushort)vv[rr][e2 * 2]), 0.f);
                    float f1 = fmaxf(z1 + bf2f((ushort)uu[rr][e2 * 2 + 1]) + bf2f((ushort)vv[rr][e2 * 2 + 1]), 0.f);
                    hh.u[e2] = pk_bf16(f0, f1);
                }
                *(short8*)&h1[nxt][r][c8] = hh.s;
            }
        }

        // ---- reduce: xor1,xor2 only (DPP); 4 partials / 16-lane group -> part[cur]
#pragma unroll
        for (int mt = 0; mt < 4; mt++)
#pragma unroll
            for (int tt = 0; tt < 4; tt++) {
                float s = 0.f;
#pragma unroll
                for (int nt = 0; nt < 2; nt++)
                    s += fmaxf(acc2[mt][nt][tt] + eb2v[nt], 0.f) * ew3v[nt];
                s += __shfl_xor(s, 1);
                s += __shfl_xor(s, 2);
                if ((m16 & 3) == 0)
                    part[cur][mt * 16 + quad * 4 + tt][wave * 4 + (m16 >> 2)] = s;
            }
        __syncthreads();   // single barrier/tile: orders h1 phase flip + part publish
    }

    // ---- tail: edge-output write for the last tile
    if (tid < MTILE) {
        int p = (ti0 + TPB - 1) * MTILE + tid;
        if (p < NPAIRS) {
            float v = eb3[0];
#pragma unroll
            for (int w = 0; w < 32; w++) v += part[(TPB - 1) & 1][tid][w];
            out_edges[b * NPAIRS + p] = sigmoidf(v);
        }
    }
}

extern "C" void kernel_launch(void* const* d_in, const int* in_sizes, int n_in,
                              void* d_out, int out_size, void* d_ws, size_t ws_size,
                              hipStream_t stream) {
    const float* z   = (const float*)d_in[0];
    const float* nw1 = (const float*)d_in[1];
    const float* nb1 = (const float*)d_in[2];
    const float* nw2 = (const float*)d_in[3];
    const float* nb2 = (const float*)d_in[4];
    const float* nw3 = (const float*)d_in[5];
    const float* nb3 = (const float*)d_in[6];
    const float* ew1 = (const float*)d_in[7];
    const float* eb1 = (const float*)d_in[8];
    const float* ew2 = (const float*)d_in[9];
    const float* eb2 = (const float*)d_in[10];
    const float* ew3 = (const float*)d_in[11];
    const float* eb3 = (const float*)d_in[12];

    char* ws = (char*)d_ws;
    int*    ptab = (int*)(ws);                       // 1225*4
    ushort* h2b  = (ushort*)(ws + 262144);           // 131072
    ushort* ew2T = (ushort*)(ws + 2031616);          // 262144
    ushort* wijT = (ushort*)(ws + 2293760);          // 262144
    float*  Zc   = (float*)(ws + 9109504);           // 262144
    ushort* UV   = (ushort*)(ws + 9371648);          // 13107200

    float* out_nodes = (float*)d_out;                // 128*6400
    float* out_edges = out_nodes + BATCH * NODE_OUT; // 128*1225

    k_prep_all<<<PREPK_NB, 256, 0, stream>>>(ew1, ew2, ew2T, wijT,
                                             z, eb1, Zc, nw1, nb1, nw2, nb2,
                                             h2b, ptab);
    k_node_uv<<<200, 256, 0, stream>>>(h2b, nw3, nb3, wijT, out_nodes, UV);
    k_edge8<<<NBLK, 512, 0, stream>>>(Zc, UV, ew2T, ew3, eb2, eb3, ptab, out_edges);
}

// Round 6
// 207.169 us; speedup vs baseline: 1.4213x; 1.0084x over previous
//
#include <hip/hip_runtime.h>
#include <hip/hip_bf16.h>
#include <math.h>

#define LATENT 256
#define HIDDEN 512
#define NODE_F 128
#define MAX_NODES 50
#define NPAIRS 1225        // 50*49/2
#define BATCH 128
#define NODE_OUT 6400      // MAX_NODES*NODE_F
#define MTILE 64           // edge rows per tile (R12-measured)
#define TPB 10             // tiles per block (20 tiles/batch = 2 blocks/batch)
#define NBLK 256           // edge grid (1 block/CU)

typedef __attribute__((ext_vector_type(8))) short short8;
typedef __attribute__((ext_vector_type(4))) float float4v;

union S8U { short8 s; unsigned int u[4]; };

__device__ __forceinline__ float bf2f(ushort u) {
    union { unsigned int i; float f; } v; v.i = ((unsigned int)u) << 16; return v.f;
}
__device__ __forceinline__ ushort f2bf(float f) {
    union { unsigned int i; float f; } v; v.f = f;
    unsigned int r = v.i + 0x7fffu + ((v.i >> 16) & 1u);   // RNE
    return (ushort)(r >> 16);
}
__device__ __forceinline__ unsigned int pk_bf16(float f0, float f1) {
    __hip_bfloat162 p = __float22bfloat162_rn(float2{f0, f1});   // v_cvt_pk_bf16_f32 (RNE)
    unsigned int w; __builtin_memcpy(&w, &p, 4); return w;
}
__device__ __forceinline__ float sigmoidf(float x) {
    return 1.0f / (1.0f + __expf(-x));
}

// ================= fused prep kernel (R11/R4 layout — measured-good) =================
// [0,800)      nw3T 64x64-tile transpose
// [800,832)    ew2T 64x64-tile transpose (8 k-tiles x 4 n-tiles)
// [832,848)    wijT U-half tiles (2 k x 8 n)
// [848,864)    wijT V-half tiles (2 k x 8 n)
// [864,1120)   Zc = z @ W_z + eb1
// [1120,1376)  fused node MLP L1+L2 -> h2b
// [1376,1381)  ptab
#define TR3_B0   0
#define EW2_B0   800
#define WIU_B0   832
#define WIV_B0   848
#define ZC_B0    864
#define ND_B0    1120
#define PT_B0    1376
#define PREPK_NB 1381

__global__ __launch_bounds__(256) void k_prep_all(
    const float* __restrict__ nw3, ushort* __restrict__ nw3T,
    const float* __restrict__ ew1, const float* __restrict__ ew2,
    ushort* __restrict__ ew2T, ushort* __restrict__ wijT,
    const float* __restrict__ z, const float* __restrict__ eb1,
    float* __restrict__ Zc,
    const float* __restrict__ nw1, const float* __restrict__ nb1,
    const float* __restrict__ nw2, const float* __restrict__ nb2,
    ushort* __restrict__ h2b, int* __restrict__ ptab)
{
    __shared__ float smem[64 * 65];
    int b = blockIdx.x;
    int tid = threadIdx.x;
    int tx = tid & 63, ty = tid >> 6;   // 64 x 4

    if (b < EW2_B0) {
        // ---- nw3 transpose, 64x64 tiles (8 k-tiles x 100 n-tiles)
        int bb = b - TR3_B0;
        int k0 = (bb & 7) * 64;
        int n0 = (bb >> 3) * 64;
#pragma unroll
        for (int r = 0; r < 16; r++) {
            int row = r * 4 + ty;
            smem[row * 65 + tx] = nw3[(k0 + row) * NODE_OUT + n0 + tx];
        }
        __syncthreads();
#pragma unroll
        for (int c = 0; c < 16; c++) {
            int n = c * 4 + ty;
            nw3T[(size_t)(n0 + n) * HIDDEN + k0 + tx] = f2bf(smem[tx * 65 + n]);
        }
    } else if (b < WIU_B0) {
        // ---- ew2T[n][k] = ew2[k][n], tiled: ew2 is 512x256
        int bb = b - EW2_B0;
        int k0 = (bb >> 2) * 64;
        int n0 = (bb & 3) * 64;
#pragma unroll
        for (int r = 0; r < 16; r++) {
            int row = r * 4 + ty;
            smem[row * 65 + tx] = ew2[(k0 + row) * 256 + n0 + tx];
        }
        __syncthreads();
#pragma unroll
        for (int c = 0; c < 16; c++) {
            int n = c * 4 + ty;
            ew2T[(n0 + n) * HIDDEN + k0 + tx] = f2bf(smem[tx * 65 + n]);
        }
    } else if (b < WIV_B0) {
        // ---- wijT U-half: wijT[n][k] = ew1[256+k][n], n<512, k<128
        int bb = b - WIU_B0;
        int k0 = (bb >> 3) * 64;
        int n0 = (bb & 7) * 64;
#pragma unroll
        for (int r = 0; r < 16; r++) {
            int row = r * 4 + ty;
            smem[row * 65 + tx] = ew1[(256 + k0 + row) * 512 + n0 + tx];
        }
        __syncthreads();
#pragma unroll
        for (int c = 0; c < 16; c++) {
            int n = c * 4 + ty;
            wijT[(n0 + n) * NODE_F + k0 + tx] = f2bf(smem[tx * 65 + n]);
        }
    } else if (b < ZC_B0) {
        // ---- wijT V-half: wijT[512+n][k] = ew1[384+k][n], n<512, k<128
        int bb = b - WIV_B0;
        int k0 = (bb >> 3) * 64;
        int n0 = (bb & 7) * 64;
#pragma unroll
        for (int r = 0; r < 16; r++) {
            int row = r * 4 + ty;
            smem[row * 65 + tx] = ew1[(384 + k0 + row) * 512 + n0 + tx];
        }
        __syncthreads();
#pragma unroll
        for (int c = 0; c < 16; c++) {
            int n = c * 4 + ty;
            wijT[(512 + n0 + n) * NODE_F + k0 + tx] = f2bf(smem[tx * 65 + n]);
        }
    } else if (b < ND_B0) {
        // ---- Zc = z @ W_z + eb1
        int b2 = b - ZC_B0;
        int r = b2 >> 1, o = (b2 & 1) * 256 + tid;
        float* zs = smem;
        zs[tid] = z[r * LATENT + tid];
        __syncthreads();
        float acc = 0.f;
#pragma unroll 8
        for (int k = 0; k < LATENT; k++) acc += zs[k] * ew1[k * HIDDEN + o];
        Zc[r * HIDDEN + o] = acc + eb1[o];
    } else if (b < PT_B0) {
        // ---- fused node MLP L1+L2
        int b2 = b - ND_B0;
        int r = b2 >> 1, half = b2 & 1;
        float* zs = smem;            // 256 floats
        float* hs = smem + 256;      // 512 floats
        zs[tid] = z[r * LATENT + tid];
        __syncthreads();
        float a0 = 0.f, a1 = 0.f;
#pragma unroll 8
        for (int k = 0; k < LATENT; k++) {
            float zk = zs[k];
            a0 += zk * nw1[k * HIDDEN + tid];
            a1 += zk * nw1[k * HIDDEN + tid + 256];
        }
        hs[tid]       = fmaxf(a0 + nb1[tid], 0.f);
        hs[tid + 256] = fmaxf(a1 + nb1[tid + 256], 0.f);
        __syncthreads();
        int o = half * 256 + tid;
        float acc = 0.f;
#pragma unroll 8
        for (int k = 0; k < HIDDEN; k++) acc += hs[k] * nw2[k * HIDDEN + o];
        acc += nb2[o];
        h2b[r * HIDDEN + o] = f2bf(fmaxf(acc, 0.f));
    } else {
        int p = (b - PT_B0) * 256 + tid;
        if (p < NPAIRS) {
            int i = 0, off = 0;
            while (p - off >= MAX_NODES - 1 - i) { off += MAX_NODES - 1 - i; ++i; }
            int j = i + 1 + (p - off);
            ptab[p] = (i << 8) | j;
        }
    }
}

// ---------------- R17: fused node-L3 + UV kernel, 8 waves/block
// grid 200 = 50 nodes x 4 batch-quarters(32 rows). 512 threads = 8 waves
// (2 waves/SIMD at <1 block/CU — doubles latency hiding vs R4's 4 waves;
// B-operand traffic per block unchanged: same nw3T/wijT slices).
// Phase 1: wave w owns 16 cols: C1[32][16] = h2b @ nw3T-slice (K=512);
//          sigmoid -> node_probs, raw bf16 -> nf_lds.
// Phase 2: wave w owns 128 UV cols (K=128), A held in 32 VGPRs.
__global__ __launch_bounds__(512, 2) void k_node_uv(
    const ushort* __restrict__ h2b, const ushort* __restrict__ nw3T,
    const float* __restrict__ nb3, const ushort* __restrict__ wijT,
    float* __restrict__ node_probs, ushort* __restrict__ UV)
{
    __shared__ ushort nf_lds[32][132];
    int tid = threadIdx.x;
    int wave = tid >> 6, lane = tid & 63;
    int m16 = lane & 15, quad = lane >> 4;
    int kk0 = quad * 8;

    int nd = blockIdx.x >> 2;            // node 0..49
    int m0 = (blockIdx.x & 3) * 32;      // batch-row quarter
    int col = nd * 128 + wave * 16 + m16;   // phase-1 col (global)

    // ---- phase 1: node layer-3 tile (32 rows x 16 cols per wave)
    float4v acc[2];
    acc[0] = (float4v)(0.f); acc[1] = (float4v)(0.f);

    const ushort* bp  = nw3T + (size_t)col * HIDDEN;
    const ushort* a0p = h2b + (m0 + m16) * HIDDEN;
    const ushort* a1p = h2b + (m0 + 16 + m16) * HIDDEN;
#pragma unroll
    for (int it = 0; it < 16; ++it) {
        int kk = it * 32 + kk0;
        short8 bfr = *(const short8*)(bp + kk);
        short8 af0 = *(const short8*)(a0p + kk);
        short8 af1 = *(const short8*)(a1p + kk);
        acc[0] = __builtin_amdgcn_mfma_f32_16x16x32_bf16(af0, bfr, acc[0], 0, 0, 0);
        acc[1] = __builtin_amdgcn_mfma_f32_16x16x32_bf16(af1, bfr, acc[1], 0, 0, 0);
    }
    float bias = nb3[col];
#pragma unroll
    for (int mf = 0; mf < 2; mf++)
#pragma unroll
        for (int t = 0; t < 4; t++) {
            int rowL = mf * 16 + quad * 4 + t;             // 0..31 local batch
            float v = acc[mf][t] + bias;
            node_probs[(size_t)(m0 + rowL) * NODE_OUT + col] = sigmoidf(v);
            nf_lds[rowL][wave * 16 + m16] = f2bf(v);
        }
    __syncthreads();

    // ---- phase 2: UV tile (32 rows x 128 cols per wave, K=128)
    short8 Areg[2][4];
#pragma unroll
    for (int mf = 0; mf < 2; mf++)
#pragma unroll
        for (int ks = 0; ks < 4; ks++)
            Areg[mf][ks] = *(const short8*)&nf_lds[mf * 16 + m16][ks * 32 + kk0];

#pragma unroll
    for (int nfi = 0; nfi < 8; ++nfi) {
        int colg = wave * 128 + nfi * 16 + m16;            // 0..1023
        const ushort* bp2 = wijT + colg * NODE_F + kk0;
        float4v u0 = (float4v)(0.f), u1 = (float4v)(0.f);
#pragma unroll
        for (int ks = 0; ks < 4; ks++) {
            short8 bfr = *(const short8*)(bp2 + ks * 32);
            u0 = __builtin_amdgcn_mfma_f32_16x16x32_bf16(Areg[0][ks], bfr, u0, 0, 0, 0);
            u1 = __builtin_amdgcn_mfma_f32_16x16x32_bf16(Areg[1][ks], bfr, u1, 0, 0, 0);
        }
#pragma unroll
        for (int t = 0; t < 4; t++) {
            int r0g = m0 + quad * 4 + t;
            UV[(size_t)(r0g * MAX_NODES + nd) * 1024 + colg]        = f2bf(u0[t]);
            UV[(size_t)((r0g + 16) * MAX_NODES + nd) * 1024 + colg] = f2bf(u1[t]);
        }
    }
}

// ---------------- fused edge, persistent-B, TPB=10, grid 256 (1 block/CU)
// R12 (measured 70.1 µs fast-chip): single barrier per tile (part
// double-buffered, out-write deferred one tile), DPP-only reduce.
// 5.24M LDS conflicts structural (b128 row-stride pigeonhole); occupancy
// pinned at 2 waves/SIMD by Breg=128 VGPR. Do not touch.
__global__ __launch_bounds__(512, 2) void k_edge8(
    const float* __restrict__ Zc, const ushort* __restrict__ UV,
    const ushort* __restrict__ ew2T, const float* __restrict__ ew3,
    const float* __restrict__ eb2, const float* __restrict__ eb3,
    const int* __restrict__ ptab, float* __restrict__ out_edges)
{
    __shared__ __align__(16) ushort h1[2][MTILE][HIDDEN + 8]; // 133,120 B
    __shared__ float part[2][MTILE][33];                      //  16,896 B
    __shared__ int uo5[TPB][MTILE], vo5[TPB][MTILE];          //   5,120 B

    int tid  = threadIdx.x;
    int blk  = blockIdx.x;
    int b    = blk >> 1;
    int ti0  = (blk & 1) * TPB;

    if (tid < MTILE) {
#pragma unroll
        for (int t = 0; t < TPB; t++) {
            int p = (ti0 + t) * MTILE + tid;
            if (p >= NPAIRS) p = NPAIRS - 1;
            int ij = ptab[p];
            uo5[t][tid] = (b * MAX_NODES + (ij >> 8)) * 1024;
            vo5[t][tid] = (b * MAX_NODES + (ij & 255)) * 1024 + 512;
        }
    }

    int wave = tid >> 6, lane = tid & 63;
    int m16 = lane & 15, quad = lane >> 4;
    int c8 = lane * 8;
    int kk0 = quad * 8;

    float4v zA = *(const float4v*)(Zc + b * HIDDEN + c8);
    float4v zB = *(const float4v*)(Zc + b * HIDDEN + c8 + 4);

    const ushort* bb0 = ew2T + (wave * 32 + m16) * HIDDEN;
    const ushort* bb1 = ew2T + (wave * 32 + 16 + m16) * HIDDEN;
    short8 Breg[16][2];
#pragma unroll
    for (int kc = 0; kc < 16; kc++) {
        Breg[kc][0] = *(const short8*)(bb0 + kc * 32 + kk0);
        Breg[kc][1] = *(const short8*)(bb1 + kc * 32 + kk0);
    }
    float eb2v[2], ew3v[2];
    eb2v[0] = eb2[wave * 32 + m16];      eb2v[1] = eb2[wave * 32 + 16 + m16];
    ew3v[0] = ew3[wave * 32 + m16];      ew3v[1] = ew3[wave * 32 + 16 + m16];

    __syncthreads();

    // ---- prologue: build tile 0 into h1[0]
#pragma unroll
    for (int rr = 0; rr < 8; rr++) {
        int r = wave * 8 + rr;
        short8 u8 = *(const short8*)(UV + uo5[0][r] + c8);
        short8 v8 = *(const short8*)(UV + vo5[0][r] + c8);
        S8U hh;
#pragma unroll
        for (int e2 = 0; e2 < 4; e2++) {
            float z0 = (e2 < 2) ? zA[e2 * 2] : zB[e2 * 2 - 4];
            float z1 = (e2 < 2) ? zA[e2 * 2 + 1] : zB[e2 * 2 - 3];
            float f0 = fmaxf(z0 + bf2f((ushort)u8[e2 * 2]) + bf2f((ushort)v8[e2 * 2]), 0.f);
            float f1 = fmaxf(z1 + bf2f((ushort)u8[e2 * 2 + 1]) + bf2f((ushort)v8[e2 * 2 + 1]), 0.f);
            hh.u[e2] = pk_bf16(f0, f1);
        }
        *(short8*)&h1[0][r][c8] = hh.s;
    }
    __syncthreads();

    for (int t = 0; t < TPB; t++) {
        int cur = t & 1, nxt = cur ^ 1;
        bool hasNext = (t + 1 < TPB);

        // ---- deferred edge-output write for tile t-1 (overlaps other waves' MFMA)
        if (t > 0 && tid < MTILE) {
            int p = (ti0 + t - 1) * MTILE + tid;
            if (p < NPAIRS) {
                float v = eb3[0];
#pragma unroll
                for (int w = 0; w < 32; w++) v += part[nxt][tid][w];
                out_edges[b * NPAIRS + p] = sigmoidf(v);
            }
        }

        float4v acc2[4][2];
#pragma unroll
        for (int mt = 0; mt < 4; mt++)
#pragma unroll
            for (int nt = 0; nt < 2; nt++) acc2[mt][nt] = (float4v)(0.f);

        short8 uu[4], vv[4];
        if (hasNext) {
#pragma unroll
            for (int rr = 0; rr < 4; rr++) {
                int r = wave * 8 + rr;
                uu[rr] = *(const short8*)(UV + uo5[t + 1][r] + c8);
                vv[rr] = *(const short8*)(UV + vo5[t + 1][r] + c8);
            }
        }
#pragma unroll
        for (int it = 0; it < 8; ++it) {
            int kk = it * 32 + kk0;
            short8 a0 = *(const short8*)&h1[cur][m16][kk];
            short8 a1 = *(const short8*)&h1[cur][16 + m16][kk];
            short8 a2 = *(const short8*)&h1[cur][32 + m16][kk];
            short8 a3 = *(const short8*)&h1[cur][48 + m16][kk];
            acc2[0][0] = __builtin_amdgcn_mfma_f32_16x16x32_bf16(a0, Breg[it][0], acc2[0][0], 0, 0, 0);
            acc2[1][0] = __builtin_amdgcn_mfma_f32_16x16x32_bf16(a1, Breg[it][0], acc2[1][0], 0, 0, 0);
            acc2[2][0] = __builtin_amdgcn_mfma_f32_16x16x32_bf16(a2, Breg[it][0], acc2[2][0], 0, 0, 0);
            acc2[3][0] = __builtin_amdgcn_mfma_f32_16x16x32_bf16(a3, Breg[it][0], acc2[3][0], 0, 0, 0);
            acc2[0][1] = __builtin_amdgcn_mfma_f32_16x16x32_bf16(a0, Breg[it][1], acc2[0][1], 0, 0, 0);
            acc2[1][1] = __builtin_amdgcn_mfma_f32_16x16x32_bf16(a1, Breg[it][1], acc2[1][1], 0, 0, 0);
            acc2[2][1] = __builtin_amdgcn_mfma_f32_16x16x32_bf16(a2, Breg[it][1], acc2[2][1], 0, 0, 0);
            acc2[3][1] = __builtin_amdgcn_mfma_f32_16x16x32_bf16(a3, Breg[it][1], acc2[3][1], 0, 0, 0);
        }
        if (hasNext) {
#pragma unroll
            for (int rr = 0; rr < 4; rr++) {
                int r = wave * 8 + rr;
                S8U hh;
#pragma unroll
                for (int e2 = 0; e2 < 4; e2++) {
                    float z0 = (e2 < 2) ? zA[e2 * 2] : zB[e2 * 2 - 4];
                    float z1 = (e2 < 2) ? zA[e2 * 2 + 1] : zB[e2 * 2 - 3];
                    float f0 = fmaxf(z0 + bf2f((ushort)uu[rr][e2 * 2]) + bf2f((ushort)vv[rr][e2 * 2]), 0.f);
                    float f1 = fmaxf(z1 + bf2f((ushort)uu[rr][e2 * 2 + 1]) + bf2f((ushort)vv[rr][e2 * 2 + 1]), 0.f);
                    hh.u[e2] = pk_bf16(f0, f1);
                }
                *(short8*)&h1[nxt][r][c8] = hh.s;
            }
#pragma unroll
            for (int rr = 0; rr < 4; rr++) {
                int r = wave * 8 + 4 + rr;
                uu[rr] = *(const short8*)(UV + uo5[t + 1][r] + c8);
                vv[rr] = *(const short8*)(UV + vo5[t + 1][r] + c8);
            }
        }
#pragma unroll
        for (int it = 8; it < 16; ++it) {
            int kk = it * 32 + kk0;
            short8 a0 = *(const short8*)&h1[cur][m16][kk];
            short8 a1 = *(const short8*)&h1[cur][16 + m16][kk];
            short8 a2 = *(const short8*)&h1[cur][32 + m16][kk];
            short8 a3 = *(const short8*)&h1[cur][48 + m16][kk];
            acc2[0][0] = __builtin_amdgcn_mfma_f32_16x16x32_bf16(a0, Breg[it][0], acc2[0][0], 0, 0, 0);
            acc2[1][0] = __builtin_amdgcn_mfma_f32_16x16x32_bf16(a1, Breg[it][0], acc2[1][0], 0, 0, 0);
            acc2[2][0] = __builtin_amdgcn_mfma_f32_16x16x32_bf16(a2, Breg[it][0], acc2[2][0], 0, 0, 0);
            acc2[3][0] = __builtin_amdgcn_mfma_f32_16x16x32_bf16(a3, Breg[it][0], acc2[3][0], 0, 0, 0);
            acc2[0][1] = __builtin_amdgcn_mfma_f32_16x16x32_bf16(a0, Breg[it][1], acc2[0][1], 0, 0, 0);
            acc2[1][1] = __builtin_amdgcn_mfma_f32_16x16x32_bf16(a1, Breg[it][1], acc2[1][1], 0, 0, 0);
            acc2[2][1] = __builtin_amdgcn_mfma_f32_16x16x32_bf16(a2, Breg[it][1], acc2[2][1], 0, 0, 0);
            acc2[3][1] = __builtin_amdgcn_mfma_f32_16x16x32_bf16(a3, Breg[it][1], acc2[3][1], 0, 0, 0);
        }
        if (hasNext) {
#pragma unroll
            for (int rr = 0; rr < 4; rr++) {
                int r = wave * 8 + 4 + rr;
                S8U hh;
#pragma unroll
                for (int e2 = 0; e2 < 4; e2++) {
                    float z0 = (e2 < 2) ? zA[e2 * 2] : zB[e2 * 2 - 4];
                    float z1 = (e2 < 2) ? zA[e2 * 2 + 1] : zB[e2 * 2 - 3];
                    float f0 = fmaxf(z0 + bf2f((ushort)uu[rr][e2 * 2]) + bf2f((ushort)vv[rr][e2 * 2]), 0.f);
                    float f1 = fmaxf(z1 + bf2f((ushort)uu[rr][e2 * 2 + 1]) + bf2f((ushort)vv[rr][e2 * 2 + 1]), 0.f);
                    hh.u[e2] = pk_bf16(f0, f1);
                }
                *(short8*)&h1[nxt][r][c8] = hh.s;
            }
        }

        // ---- reduce: xor1,xor2 only (DPP); 4 partials / 16-lane group -> part[cur]
#pragma unroll
        for (int mt = 0; mt < 4; mt++)
#pragma unroll
            for (int tt = 0; tt < 4; tt++) {
                float s = 0.f;
#pragma unroll
                for (int nt = 0; nt < 2; nt++)
                    s += fmaxf(acc2[mt][nt][tt] + eb2v[nt], 0.f) * ew3v[nt];
                s += __shfl_xor(s, 1);
                s += __shfl_xor(s, 2);
                if ((m16 & 3) == 0)
                    part[cur][mt * 16 + quad * 4 + tt][wave * 4 + (m16 >> 2)] = s;
            }
        __syncthreads();   // single barrier/tile: orders h1 phase flip + part publish
    }

    // ---- tail: edge-output write for the last tile
    if (tid < MTILE) {
        int p = (ti0 + TPB - 1) * MTILE + tid;
        if (p < NPAIRS) {
            float v = eb3[0];
#pragma unroll
            for (int w = 0; w < 32; w++) v += part[(TPB - 1) & 1][tid][w];
            out_edges[b * NPAIRS + p] = sigmoidf(v);
        }
    }
}

extern "C" void kernel_launch(void* const* d_in, const int* in_sizes, int n_in,
                              void* d_out, int out_size, void* d_ws, size_t ws_size,
                              hipStream_t stream) {
    const float* z   = (const float*)d_in[0];
    const float* nw1 = (const float*)d_in[1];
    const float* nb1 = (const float*)d_in[2];
    const float* nw2 = (const float*)d_in[3];
    const float* nb2 = (const float*)d_in[4];
    const float* nw3 = (const float*)d_in[5];
    const float* nb3 = (const float*)d_in[6];
    const float* ew1 = (const float*)d_in[7];
    const float* eb1 = (const float*)d_in[8];
    const float* ew2 = (const float*)d_in[9];
    const float* eb2 = (const float*)d_in[10];
    const float* ew3 = (const float*)d_in[11];
    const float* eb3 = (const float*)d_in[12];

    char* ws = (char*)d_ws;
    int*    ptab = (int*)(ws);                       // 1225*4
    ushort* h2b  = (ushort*)(ws + 262144);           // 131072
    ushort* ew2T = (ushort*)(ws + 2031616);          // 262144
    ushort* wijT = (ushort*)(ws + 2293760);          // 262144
    ushort* nw3T = (ushort*)(ws + 2555904);          // 6553600
    float*  Zc   = (float*)(ws + 9109504);           // 262144
    ushort* UV   = (ushort*)(ws + 9371648);          // 13107200

    float* out_nodes = (float*)d_out;                // 128*6400
    float* out_edges = out_nodes + BATCH * NODE_OUT; // 128*1225

    k_prep_all<<<PREPK_NB, 256, 0, stream>>>(nw3, nw3T, ew1, ew2, ew2T, wijT,
                                             z, eb1, Zc, nw1, nb1, nw2, nb2,
                                             h2b, ptab);
    k_node_uv<<<200, 512, 0, stream>>>(h2b, nw3T, nb3, wijT, out_nodes, UV);
    k_edge8<<<NBLK, 512, 0, stream>>>(Zc, UV, ew2T, ew3, eb2, eb3, ptab, out_edges);
}